// Round 5
// baseline (1277.299 us; speedup 1.0000x reference)
//
#include <hip/hip_runtime.h>
#include <math.h>

#define BKS 60      // B*K sequences
#define TL  1000    // T
#define NF  128     // N features
#define SD  12      // state dim S
#define NCH 32      // scan chunks of 32 (ap/hfb/hinit granularity)
#define NTOK (BKS*TL)
#define CLEN 32     // k_front tile (1 scan chunk)
#define CL2 64      // k_back tile (2 scan chunks)
#define CROSS_NBLK ((NTOK + CL2 - 1)/CL2)   // 938

// row-keyed XOR swizzles (bits 2..4 of float col index, float4-preserving)
#define CSW(r) ((((r)>>2)&7)<<2)   // k_front xs: hot reads have rows 4-strided
#define SRK(r) ((((r)>>3)&7)<<2)   // k_back xs: rows 8-strided across lanes

__device__ __forceinline__ float siluf(float x){ return x / (1.f + __expf(-x)); }
__device__ __forceinline__ float softplusf(float x){
  if (x > 20.f) return x;
  float e = __expf(x);
  return (x < -20.f) ? e : __logf(1.f + e);
}

// ---- K0: x (B,N,T,K) -> seq (B*K, T, N), one block per (b,t)
__global__ __launch_bounds__(256) void k_ingest(const float* __restrict__ x, float* __restrict__ seq){
  const int b = blockIdx.x / TL, t = blockIdx.x % TL;
  __shared__ float tile[30*NF];
  for (int e = threadIdx.x; e < 30*NF; e += 256){
    int n = e / 30, k = e - n*30;
    tile[k*NF + n] = x[((size_t)(b*NF + n)*TL + t)*30 + k];
  }
  __syncthreads();
  const size_t base = ((size_t)b*30)*TL*NF + (size_t)t*NF;
  for (int e = threadIdx.x; e < 30*NF; e += 256){
    int k = e >> 7, n = e & 127;
    seq[base + (size_t)k*TL*NF + n] = tile[e];
  }
}

// ---- k_front (R5): 32-token tile, 22016 B LDS. LN -> in_proj -> conv+silu ->
// xproj -> dt -> scan pass1. 1920 blocks. Occupancy experiment: previous 38-41KB
// versions all pinned at 2 blocks/CU (Occupancy ~24%); 22KB should give >=4.
__global__ __launch_bounds__(256) void k_front(
    const float* __restrict__ seq,
    const float* __restrict__ lnw, const float* __restrict__ lnb,
    const float* __restrict__ iw, const float* __restrict__ ib,
    const float* __restrict__ cw, const float* __restrict__ cb,
    const float* __restrict__ xw,
    const float* __restrict__ dw, const float* __restrict__ db,
    const float* __restrict__ alog,
    float* __restrict__ zb, float* __restrict__ xcc,
    float* __restrict__ dcb, float* __restrict__ bcb,
    float* __restrict__ ap, float* __restrict__ hfb){
  __shared__ float smem[5504];     // 22016 B
  float* xs   = smem;              // [35][128]: row 0..2 = halo toks t0-3..t0-1 (LN out),
                                   // row 3+t = token t LN out; after conv: row t = xc tok t
  float* sdbc = smem + 4480;       // [32][32]

  const int bid = blockIdx.x;
  const int sq = bid >> 5, cb2 = bid & 31;
  const int t0 = cb2 * CLEN;
  const int lim = (TL - t0 < CLEN) ? (TL - t0) : CLEN;
  const int tid = threadIdx.x;

  // ---- P0: LayerNorm rows 0..34 (token = t0-3+row; zeros when out of range)
  {
    const int j = tid >> 4, l16 = tid & 15;
    const float4 w0 = *(const float4*)(lnw + l16*8);
    const float4 w1 = *(const float4*)(lnw + l16*8 + 4);
    const float4 b0 = *(const float4*)(lnb + l16*8);
    const float4 b1 = *(const float4*)(lnb + l16*8 + 4);
    const float lw[8] = {w0.x,w0.y,w0.z,w0.w, w1.x,w1.y,w1.z,w1.w};
    const float lb[8] = {b0.x,b0.y,b0.z,b0.w, b1.x,b1.y,b1.z,b1.w};
    for (int it = 0; it < 3; ++it){
      const int row = j + 16*it;
      if (row >= 35) break;
      const int tok = t0 - 3 + row;
      const bool valid = (tok >= 0) && (tok < TL);
      float v[8]; float s = 0.f, s2 = 0.f;
      if (valid){
        const float* sp = seq + ((size_t)sq*TL + tok)*NF + l16*8;
        const float4 a0 = *(const float4*)sp;
        const float4 a1 = *(const float4*)(sp + 4);
        v[0]=a0.x; v[1]=a0.y; v[2]=a0.z; v[3]=a0.w;
        v[4]=a1.x; v[5]=a1.y; v[6]=a1.z; v[7]=a1.w;
        #pragma unroll
        for (int i = 0; i < 8; ++i){ s += v[i]; s2 += v[i]*v[i]; }
      } else {
        #pragma unroll
        for (int i = 0; i < 8; ++i) v[i] = 0.f;
      }
      #pragma unroll
      for (int m = 1; m < 16; m <<= 1){ s += __shfl_xor(s, m, 64); s2 += __shfl_xor(s2, m, 64); }
      const float mean = s * (1.f/128.f);
      const float rstd = rsqrtf(s2*(1.f/128.f) - mean*mean + 1e-5f);
      const int sk = CSW(row);
      float o[8];
      #pragma unroll
      for (int i = 0; i < 8; ++i)
        o[i] = valid ? ((v[i]-mean)*rstd*lw[i] + lb[i]) : 0.f;
      *(float4*)&xs[row*NF + ((l16*8)     ^ sk)] = make_float4(o[0],o[1],o[2],o[3]);
      *(float4*)&xs[row*NF + ((l16*8 + 4) ^ sk)] = make_float4(o[4],o[5],o[6],o[7]);
    }
  }
  __syncthreads();

  // ---- P1: in_proj GEMM. og (tid>>3): 8 outs; tg (tid&7): 4 toks. acc[8][4].
  const int og = tid >> 3;     // 0..31
  const int tg = tid & 7;      // 0..7
  float acc[8][4];
  #pragma unroll
  for (int o = 0; o < 8; ++o)
    #pragma unroll
    for (int j = 0; j < 4; ++j) acc[o][j] = 0.f;
  const float* wb = iw + (size_t)(og*8)*NF;
  for (int k4 = 0; k4 < 32; ++k4){
    const int kk = k4*4;
    float4 xv[4];
    #pragma unroll
    for (int j = 0; j < 4; ++j){
      const int row = 3 + tg*4 + j;
      xv[j] = *(const float4*)&xs[row*NF + (kk ^ CSW(row))];
    }
    #pragma unroll
    for (int o = 0; o < 8; ++o){
      const float4 w4 = *(const float4*)(wb + (size_t)o*NF + kk);
      #pragma unroll
      for (int j = 0; j < 4; ++j){
        acc[o][j] = fmaf(w4.x, xv[j].x, acc[o][j]);
        acc[o][j] = fmaf(w4.y, xv[j].y, acc[o][j]);
        acc[o][j] = fmaf(w4.z, xv[j].z, acc[o][j]);
        acc[o][j] = fmaf(w4.w, xv[j].w, acc[o][j]);
      }
    }
  }
  // halo mini-GEMM: tid<192: wave-uniform row hh, outs oc & oc+64 (xc outs only)
  float hv0 = 0.f, hv1 = 0.f;
  const int hh = tid >> 6;
  const int oc = tid & 63;
  if (tid < 192){
    for (int k4 = 0; k4 < 32; ++k4){
      const int kk = k4*4;
      const float4 xh4 = *(const float4*)&xs[hh*NF + kk];   // CSW(0..2)=0
      const float4 wa = *(const float4*)(iw + (size_t)oc*NF + kk);
      const float4 wc = *(const float4*)(iw + (size_t)(oc+64)*NF + kk);
      hv0 = fmaf(wa.w, xh4.w, fmaf(wa.z, xh4.z, fmaf(wa.y, xh4.y, fmaf(wa.x, xh4.x, hv0))));
      hv1 = fmaf(wc.w, xh4.w, fmaf(wc.z, xh4.z, fmaf(wc.y, xh4.y, fmaf(wc.x, xh4.x, hv1))));
    }
  }
  float bo[8];
  #pragma unroll
  for (int i = 0; i < 8; ++i) bo[i] = ib[og*8 + i];
  // z epilogue (register-only, before barrier)
  if (og >= 16){
    #pragma unroll
    for (int j = 0; j < 4; ++j){
      const int lt = tg*4 + j;
      if (lt >= lim) continue;
      float* dst = zb + ((size_t)sq*TL + t0 + lt)*NF + (og-16)*8;
      *(float4*)dst       = make_float4(acc[0][j]+bo[0], acc[1][j]+bo[1], acc[2][j]+bo[2], acc[3][j]+bo[3]);
      *(float4*)(dst + 4) = make_float4(acc[4][j]+bo[4], acc[5][j]+bo[5], acc[6][j]+bo[6], acc[7][j]+bo[7]);
    }
  }
  __syncthreads();   // all xs reads done -> may overwrite
  if (og < 16){
    #pragma unroll
    for (int j = 0; j < 4; ++j){
      const int row = 3 + tg*4 + j;          // xc token (tg*4+j) staged at row 3+t
      const int sk = CSW(row);
      *(float4*)&xs[row*NF + ((og*8)     ^ sk)] = make_float4(acc[0][j]+bo[0], acc[1][j]+bo[1], acc[2][j]+bo[2], acc[3][j]+bo[3]);
      *(float4*)&xs[row*NF + ((og*8 + 4) ^ sk)] = make_float4(acc[4][j]+bo[4], acc[5][j]+bo[5], acc[6][j]+bo[6], acc[7][j]+bo[7]);
    }
  }
  if (tid < 192){
    const bool hvalid = (t0 - 3 + hh) >= 0;
    xs[hh*NF + oc]      = hvalid ? (hv0 + ib[oc])      : 0.f;   // CSW(hh)=0
    xs[hh*NF + oc + 64] = hvalid ? (hv1 + ib[oc + 64]) : 0.f;
  }
  __syncthreads();

  // ---- P2: conv + silu. Output token r -> xs row r (shift down 3), two halves,
  // reg-stage inputs (rows r..r+3 hold xc tokens r-3..r) before overwriting.
  for (int half = 0; half < 2; ++half){
    float4 xin[2][4];
    #pragma unroll
    for (int i = 0; i < 2; ++i){
      const int e4 = tid + i*256;
      const int r = half*16 + (e4 >> 5);
      const int n4 = (e4 & 31) << 2;
      #pragma unroll
      for (int q = 0; q < 4; ++q){
        const int row = r + q;
        xin[i][q] = *(const float4*)&xs[row*NF + (n4 ^ CSW(row))];
      }
    }
    __syncthreads();
    #pragma unroll
    for (int i = 0; i < 2; ++i){
      const int e4 = tid + i*256;
      const int r = half*16 + (e4 >> 5);
      const int n4 = (e4 & 31) << 2;
      const float4 c0 = *(const float4*)(cw + (size_t)(n4+0)*4);
      const float4 c1 = *(const float4*)(cw + (size_t)(n4+1)*4);
      const float4 c2 = *(const float4*)(cw + (size_t)(n4+2)*4);
      const float4 c3 = *(const float4*)(cw + (size_t)(n4+3)*4);
      float4 a = *(const float4*)(cb + n4);
      a.x = fmaf(xin[i][3].x, c0.w, fmaf(xin[i][2].x, c0.z, fmaf(xin[i][1].x, c0.y, fmaf(xin[i][0].x, c0.x, a.x))));
      a.y = fmaf(xin[i][3].y, c1.w, fmaf(xin[i][2].y, c1.z, fmaf(xin[i][1].y, c1.y, fmaf(xin[i][0].y, c1.x, a.y))));
      a.z = fmaf(xin[i][3].z, c2.w, fmaf(xin[i][2].z, c2.z, fmaf(xin[i][1].z, c2.y, fmaf(xin[i][0].z, c2.x, a.z))));
      a.w = fmaf(xin[i][3].w, c3.w, fmaf(xin[i][2].w, c3.z, fmaf(xin[i][1].w, c3.y, fmaf(xin[i][0].w, c3.x, a.w))));
      a.x = siluf(a.x); a.y = siluf(a.y); a.z = siluf(a.z); a.w = siluf(a.w);
      *(float4*)&xs[r*NF + (n4 ^ CSW(r))] = a;
      if (r < lim) *(float4*)(xcc + ((size_t)sq*TL + t0 + r)*NF + n4) = a;
    }
    __syncthreads();
  }

  // ---- P3: xproj -> sdbc[32][32]. Strided token map keeps CSW keys distinct.
  {
    const int og2 = tid >> 5;                              // 0..7, outs og2*4..+3
    const int t = ((tid & 7) << 2) | ((tid >> 3) & 3);     // 0..31, stride-4 in lane
    const int sk = CSW(t);
    float pa[4];
    #pragma unroll
    for (int o = 0; o < 4; ++o) pa[o] = 0.f;
    const float* xwb = xw + (size_t)(og2*4)*NF;
    for (int k4 = 0; k4 < 32; ++k4){
      const int kk = k4*4;
      const float4 xv0 = *(const float4*)&xs[t*NF + (kk ^ sk)];
      #pragma unroll
      for (int o = 0; o < 4; ++o){
        const float4 w4 = *(const float4*)(xwb + (size_t)o*NF + kk);
        pa[o] = fmaf(w4.w, xv0.w, fmaf(w4.z, xv0.z, fmaf(w4.y, xv0.y, fmaf(w4.x, xv0.x, pa[o]))));
      }
    }
    *(float4*)&sdbc[t*32 + og2*4] = make_float4(pa[0],pa[1],pa[2],pa[3]);
  }
  __syncthreads();

  // ---- P4: dcb/bcb global copies + scan pass1 (dt inline, 6 states per thread)
  if (tid < 64){
    const int t = tid >> 1, q = tid & 1;
    if (t < lim)
      *(float4*)(dcb + ((size_t)sq*TL + t0 + t)*8 + q*4) = *(const float4*)&sdbc[t*32 + q*4];
  }
  if (tid < 192){
    const int t = tid / 6, q = tid - t*6;
    if (t < lim)
      *(float4*)(bcb + ((size_t)sq*TL + t0 + t)*24 + q*4) = *(const float4*)&sdbc[t*32 + 8 + q*4];
  }
  {
    const int n = tid & 127, p = tid >> 7;   // p wave-uniform; 6 states each
    float Av[6], h[6];
    #pragma unroll
    for (int s = 0; s < 6; ++s){
      Av[s] = -__expf(alog[(size_t)n*SD + p*6 + s]);
      h[s] = 0.f;
    }
    const float4 dw0 = *(const float4*)(dw + (size_t)n*8);
    const float4 dw1 = *(const float4*)(dw + (size_t)n*8 + 4);
    const float dbn = db[n];
    float dts = 0.f;
    for (int tt = 0; tt < lim; ++tt){
      const float4 q0 = *(const float4*)&sdbc[tt*32];
      const float4 q1 = *(const float4*)&sdbc[tt*32 + 4];
      float da = dbn;
      da = fmaf(q0.x,dw0.x, da); da = fmaf(q0.y,dw0.y, da);
      da = fmaf(q0.z,dw0.z, da); da = fmaf(q0.w,dw0.w, da);
      da = fmaf(q1.x,dw1.x, da); da = fmaf(q1.y,dw1.y, da);
      da = fmaf(q1.z,dw1.z, da); da = fmaf(q1.w,dw1.w, da);
      const float dtv = softplusf(da);
      const float xcv = xs[tt*NF + (n ^ CSW(tt))];
      float Bv[6];
      const float* br = sdbc + tt*32 + 8 + p*6;
      if (p == 0){
        const float4 a = *(const float4*)br;
        const float2 b = *(const float2*)(br + 4);
        Bv[0]=a.x; Bv[1]=a.y; Bv[2]=a.z; Bv[3]=a.w; Bv[4]=b.x; Bv[5]=b.y;
      } else {
        const float2 a = *(const float2*)br;
        const float4 b = *(const float4*)(br + 2);
        Bv[0]=a.x; Bv[1]=a.y; Bv[2]=b.x; Bv[3]=b.y; Bv[4]=b.z; Bv[5]=b.w;
      }
      const float dx = dtv * xcv;
      dts += dtv;
      #pragma unroll
      for (int s = 0; s < 6; ++s){
        const float dA = __expf(dtv*Av[s]);
        h[s] = fmaf(dA, h[s], dx*Bv[s]);
      }
    }
    const size_t base = ((size_t)(sq*NCH + cb2))*SD*NF + n;
    #pragma unroll
    for (int s = 0; s < 6; ++s){
      ap [base + (p*6+s)*NF] = __expf(Av[s]*dts);
      hfb[base + (p*6+s)*NF] = h[s];
    }
  }
}

// ---- K3b: sequential combine across chunks (unchanged)
__global__ __launch_bounds__(128) void k_scan_combine(
    const float* __restrict__ ap, const float* __restrict__ hfb, float* __restrict__ hinit){
  const int sq = blockIdx.x;
  const int n = threadIdx.x;
  float h[SD];
  #pragma unroll
  for (int s = 0; s < SD; ++s) h[s] = 0.f;
  for (int c = 0; c < NCH; ++c){
    const size_t base = ((size_t)sq*NCH + c)*SD*NF + n;
    #pragma unroll
    for (int s = 0; s < SD; ++s){
      hinit[base + s*NF] = h[s];
      h[s] = fmaf(ap[base + s*NF], h[s], hfb[base + s*NF]);
    }
  }
}

// ---- k_back: scan pass2 (y -> LDS) -> output GEMM -> seq += y@ow^T+ob. (R4 form)
__global__ __launch_bounds__(256) void k_back(
    const float* __restrict__ dcb, const float* __restrict__ bcb,
    const float* __restrict__ xcc, const float* __restrict__ zb,
    const float* __restrict__ dw, const float* __restrict__ db,
    const float* __restrict__ alog, const float* __restrict__ hinit,
    const float* __restrict__ Dv,
    const float* __restrict__ ow, const float* __restrict__ ob,
    float* __restrict__ seq){
  __shared__ float xs[CL2*NF];   // 32768 B; y (SRK-swizzled)
  const int bid = blockIdx.x;
  const int sq = bid >> 4, cb2 = bid & 15;
  const int t0 = cb2 * CL2;
  const int lim = (TL - t0 < CL2) ? (TL - t0) : CL2;
  const int tid = threadIdx.x;

  {
    const int n = tid & 127, ch = tid >> 7;
    float Av[SD];
    {
      const float4 a0 = *(const float4*)(alog + (size_t)n*SD);
      const float4 a1 = *(const float4*)(alog + (size_t)n*SD + 4);
      const float4 a2 = *(const float4*)(alog + (size_t)n*SD + 8);
      const float t_[SD] = {a0.x,a0.y,a0.z,a0.w, a1.x,a1.y,a1.z,a1.w, a2.x,a2.y,a2.z,a2.w};
      #pragma unroll
      for (int s = 0; s < SD; ++s) Av[s] = -__expf(t_[s]);
    }
    const float4 dw0 = *(const float4*)(dw + (size_t)n*8);
    const float4 dw1 = *(const float4*)(dw + (size_t)n*8 + 4);
    const float dbn = db[n];
    const float dvn = Dv[n];
    float h[SD];
    {
      const size_t hb = ((size_t)(sq*NCH + cb2*2 + ch))*SD*NF + n;
      #pragma unroll
      for (int s = 0; s < SD; ++s) h[s] = hinit[hb + s*NF];
    }
    int steps = lim - ch*32; if (steps < 0) steps = 0; if (steps > 32) steps = 32;
    for (int tt = 0; tt < steps; ++tt){
      const int t = ch*32 + tt;
      const size_t gt = (size_t)sq*TL + t0 + t;
      const float4 d0 = *(const float4*)(dcb + gt*8);
      const float4 d1 = *(const float4*)(dcb + gt*8 + 4);
      float da = dbn;
      da = fmaf(d0.x,dw0.x, da); da = fmaf(d0.y,dw0.y, da);
      da = fmaf(d0.z,dw0.z, da); da = fmaf(d0.w,dw0.w, da);
      da = fmaf(d1.x,dw1.x, da); da = fmaf(d1.y,dw1.y, da);
      da = fmaf(d1.z,dw1.z, da); da = fmaf(d1.w,dw1.w, da);
      const float dtv = softplusf(da);
      const float xcv = xcc[gt*NF + n];
      const float zv  = zb [gt*NF + n];
      const float4 B0 = *(const float4*)(bcb + gt*24);
      const float4 B1 = *(const float4*)(bcb + gt*24 + 4);
      const float4 B2 = *(const float4*)(bcb + gt*24 + 8);
      const float4 C0 = *(const float4*)(bcb + gt*24 + 12);
      const float4 C1 = *(const float4*)(bcb + gt*24 + 16);
      const float4 C2 = *(const float4*)(bcb + gt*24 + 20);
      const float Bv[SD] = {B0.x,B0.y,B0.z,B0.w, B1.x,B1.y,B1.z,B1.w, B2.x,B2.y,B2.z,B2.w};
      const float Cv[SD] = {C0.x,C0.y,C0.z,C0.w, C1.x,C1.y,C1.z,C1.w, C2.x,C2.y,C2.z,C2.w};
      const float dx = dtv * xcv;
      float y = 0.f;
      #pragma unroll
      for (int s = 0; s < SD; ++s){
        const float dA = __expf(dtv*Av[s]);
        h[s] = fmaf(dA, h[s], dx*Bv[s]);
        y = fmaf(h[s], Cv[s], y);
      }
      const float yf = fmaf(dvn, xcv, y) * siluf(zv);
      xs[t*NF + (n ^ SRK(t))] = yf;
    }
  }
  if (lim < CL2){
    for (int e = tid; e < (CL2 - lim)*NF; e += 256) xs[lim*NF + e] = 0.f;
  }
  __syncthreads();

  {
    const int og = tid >> 4;     // 0..15, outs og*8..+7
    const int tg = tid & 15;     // 0..15, toks tg*4..+3
    float acc[8][4];
    #pragma unroll
    for (int o = 0; o < 8; ++o)
      #pragma unroll
      for (int j = 0; j < 4; ++j) acc[o][j] = 0.f;
    const float* owb = ow + (size_t)(og*8)*NF;
    for (int k4 = 0; k4 < 32; ++k4){
      const int kk = k4*4;
      float4 xv[4];
      #pragma unroll
      for (int j = 0; j < 4; ++j){
        const int row = tg*4 + j;
        xv[j] = *(const float4*)&xs[row*NF + (kk ^ SRK(row))];
      }
      #pragma unroll
      for (int o = 0; o < 8; ++o){
        const float4 w4 = *(const float4*)(owb + (size_t)o*NF + kk);
        #pragma unroll
        for (int j = 0; j < 4; ++j){
          acc[o][j] = fmaf(w4.x, xv[j].x, acc[o][j]);
          acc[o][j] = fmaf(w4.y, xv[j].y, acc[o][j]);
          acc[o][j] = fmaf(w4.z, xv[j].z, acc[o][j]);
          acc[o][j] = fmaf(w4.w, xv[j].w, acc[o][j]);
        }
      }
    }
    float bo[8];
    #pragma unroll
    for (int i = 0; i < 8; ++i) bo[i] = ob[og*8 + i];
    #pragma unroll
    for (int j = 0; j < 4; ++j){
      const int lt = tg*4 + j;
      if (lt >= lim) continue;
      float* dst = seq + ((size_t)sq*TL + t0 + lt)*NF + og*8;
      float4 s0 = *(float4*)dst;
      float4 s1 = *(float4*)(dst + 4);
      s0.x += acc[0][j]+bo[0]; s0.y += acc[1][j]+bo[1];
      s0.z += acc[2][j]+bo[2]; s0.w += acc[3][j]+bo[3];
      s1.x += acc[4][j]+bo[4]; s1.y += acc[5][j]+bo[5];
      s1.z += acc[6][j]+bo[6]; s1.w += acc[7][j]+bo[7];
      *(float4*)dst = s0;
      *(float4*)(dst + 4) = s1;
    }
  }
}

// ---- k_cross: cross GEMM -> LN -> gelu -> +main -> LN -> transposed out. 64 tok/block.
__global__ __launch_bounds__(256) void k_cross(
    const float* __restrict__ seq,
    const float* __restrict__ cbw, const float* __restrict__ cbb,
    const float* __restrict__ clnw, const float* __restrict__ clnb,
    const float* __restrict__ flnw, const float* __restrict__ flnb,
    float* __restrict__ out){
  __shared__ float xs[CL2*NF];
  const int tid = threadIdx.x;
  const int tok0 = blockIdx.x * CL2;

  #pragma unroll
  for (int i = 0; i < 8; ++i){
    const int nq = (tid & 15) + ((i >> 2) << 4);
    const int r  = ((tid >> 4) & 15) + ((i & 3) << 4);
    const int tok = tok0 + r;
    float4 v = make_float4(0.f,0.f,0.f,0.f);
    if (tok < NTOK){
      const int b = tok / 30000, rr = tok - b*30000;
      const int t = rr / 30, k = rr - t*30;
      v = *(const float4*)(seq + ((size_t)(b*30 + k)*TL + t)*NF + nq*4);
    }
    *(float4*)&xs[r*NF + nq*4] = v;
  }
  __syncthreads();

  const int o4g = tid & 31, t8 = tid >> 5;
  float acc[4][8];
  #pragma unroll
  for (int o = 0; o < 4; ++o)
    #pragma unroll
    for (int j = 0; j < 8; ++j) acc[o][j] = 0.f;
  const float* wb = cbw + (size_t)(o4g*4)*NF;
  for (int k4 = 0; k4 < 32; ++k4){
    const int kk = k4*4;
    float4 xv[8];
    #pragma unroll
    for (int j = 0; j < 8; ++j)
      xv[j] = *(const float4*)&xs[(t8*8+j)*NF + kk];
    #pragma unroll
    for (int o = 0; o < 4; ++o){
      const float4 w4 = *(const float4*)(wb + (size_t)o*NF + kk);
      #pragma unroll
      for (int j = 0; j < 8; ++j){
        acc[o][j] = fmaf(w4.x, xv[j].x, acc[o][j]);
        acc[o][j] = fmaf(w4.y, xv[j].y, acc[o][j]);
        acc[o][j] = fmaf(w4.z, xv[j].z, acc[o][j]);
        acc[o][j] = fmaf(w4.w, xv[j].w, acc[o][j]);
      }
    }
  }

  const float4 cbb4 = *(const float4*)(cbb + o4g*4);
  const float4 cw4  = *(const float4*)(clnw + o4g*4);
  const float4 cb4  = *(const float4*)(clnb + o4g*4);
  const float4 fw4  = *(const float4*)(flnw + o4g*4);
  const float4 fb4  = *(const float4*)(flnb + o4g*4);
  float4 rv[8];
  #pragma unroll
  for (int j = 0; j < 8; ++j){
    float cv[4] = {acc[0][j]+cbb4.x, acc[1][j]+cbb4.y, acc[2][j]+cbb4.z, acc[3][j]+cbb4.w};
    float s = cv[0]+cv[1]+cv[2]+cv[3];
    float s2 = cv[0]*cv[0]+cv[1]*cv[1]+cv[2]*cv[2]+cv[3]*cv[3];
    #pragma unroll
    for (int m = 1; m < 32; m <<= 1){ s += __shfl_xor(s, m, 64); s2 += __shfl_xor(s2, m, 64); }
    const float mu = s * (1.f/128.f);
    const float rs = rsqrtf(s2*(1.f/128.f) - mu*mu + 1e-5f);
    const float clw[4] = {cw4.x,cw4.y,cw4.z,cw4.w};
    const float clb[4] = {cb4.x,cb4.y,cb4.z,cb4.w};
    const float4 mv = *(const float4*)&xs[(t8*8+j)*NF + o4g*4];
    const float mvv[4] = {mv.x,mv.y,mv.z,mv.w};
    float res[4]; float rsum = 0.f, rsum2 = 0.f;
    #pragma unroll
    for (int i = 0; i < 4; ++i){
      const float cn = (cv[i] - mu)*rs*clw[i] + clb[i];
      const float g = 0.5f*cn*(1.f + erff(cn*0.70710678118f));
      res[i] = mvv[i] + g;
      rsum += res[i]; rsum2 += res[i]*res[i];
    }
    #pragma unroll
    for (int m = 1; m < 32; m <<= 1){ rsum += __shfl_xor(rsum, m, 64); rsum2 += __shfl_xor(rsum2, m, 64); }
    const float mu2 = rsum * (1.f/128.f);
    const float rs2 = rsqrtf(rsum2*(1.f/128.f) - mu2*mu2 + 1e-5f);
    const float flw[4] = {fw4.x,fw4.y,fw4.z,fw4.w};
    const float flb[4] = {fb4.x,fb4.y,fb4.z,fb4.w};
    rv[j] = make_float4((res[0]-mu2)*rs2*flw[0]+flb[0], (res[1]-mu2)*rs2*flw[1]+flb[1],
                        (res[2]-mu2)*rs2*flw[2]+flb[2], (res[3]-mu2)*rs2*flw[3]+flb[3]);
  }
  __syncthreads();
  float* fs = xs;
  #pragma unroll
  for (int j = 0; j < 8; ++j)
    *(float4*)&fs[(t8*8+j)*NF + o4g*4] = rv[j];
  __syncthreads();

  {
    const int nn = tid >> 1, hh = tid & 1;
    #pragma unroll
    for (int q = 0; q < 8; ++q){
      const int tbase = hh*32 + q*4;
      const int tok = tok0 + tbase;
      if (tok >= NTOK) continue;
      const int b = tok / 30000, rr = tok - b*30000;
      float4 v;
      v.x = fs[(tbase+0)*NF + nn];
      v.y = fs[(tbase+1)*NF + nn];
      v.z = fs[(tbase+2)*NF + nn];
      v.w = fs[(tbase+3)*NF + nn];
      *(float4*)(out + ((size_t)(b*NF + nn))*30000 + rr) = v;
    }
  }
}

extern "C" void kernel_launch(void* const* d_in, const int* in_sizes, int n_in,
                              void* d_out, int out_size, void* d_ws, size_t ws_size,
                              hipStream_t stream){
  const float* x       = (const float*)d_in[0];
  const float* ln_w    = (const float*)d_in[1];
  const float* ln_b    = (const float*)d_in[2];
  const float* in_w    = (const float*)d_in[3];
  const float* in_b    = (const float*)d_in[4];
  const float* conv_w  = (const float*)d_in[5];
  const float* conv_b  = (const float*)d_in[6];
  const float* xp_w    = (const float*)d_in[7];
  const float* dtp_w   = (const float*)d_in[8];
  const float* dtp_b   = (const float*)d_in[9];
  const float* A_log   = (const float*)d_in[10];
  const float* Dv      = (const float*)d_in[11];
  const float* out_w   = (const float*)d_in[12];
  const float* out_b   = (const float*)d_in[13];
  const float* cb_w    = (const float*)d_in[14];
  const float* cb_b    = (const float*)d_in[15];
  const float* cb_ln_w = (const float*)d_in[16];
  const float* cb_ln_b = (const float*)d_in[17];
  const float* fin_ln_w= (const float*)d_in[18];
  const float* fin_ln_b= (const float*)d_in[19];
  float* out = (float*)d_out;

  const size_t SEQSZ = (size_t)BKS*TL*NF;        // 7,680,000 floats
  const size_t CHSZ  = (size_t)BKS*NCH*SD*NF;    // 2,949,120 floats
  const size_t DCBSZ = (size_t)NTOK*8;
  const size_t BCBSZ = (size_t)NTOK*24;
  float* ws   = (float*)d_ws;
  float* seq  = ws;
  float* zb   = ws + SEQSZ;
  float* xcc  = ws + 2*SEQSZ;
  float* dcb  = ws + 3*SEQSZ;
  float* bcb  = dcb + DCBSZ;
  float* ap   = bcb + BCBSZ;
  float* hfb  = ap + CHSZ;
  float* hinit= hfb + CHSZ;
  const size_t BASE = 3*SEQSZ + DCBSZ + BCBSZ + 3*CHSZ;
  if (ws_size < BASE*sizeof(float)) return;

  k_ingest<<<2*TL, 256, 0, stream>>>(x, seq);
  for (int l = 0; l < 4; ++l){
    k_front<<<BKS*NCH, 256, 0, stream>>>(seq,
        ln_w + l*NF, ln_b + l*NF,
        in_w + (size_t)l*2*NF*NF, in_b + (size_t)l*2*NF,
        conv_w + (size_t)l*NF*4, conv_b + l*NF,
        xp_w + (size_t)l*32*NF,
        dtp_w + (size_t)l*NF*8, dtp_b + l*NF,
        A_log + (size_t)l*NF*SD,
        zb, xcc, dcb, bcb, ap, hfb);
    k_scan_combine<<<BKS, NF, 0, stream>>>(ap, hfb, hinit);
    k_back<<<BKS*16, 256, 0, stream>>>(dcb, bcb, xcc, zb,
        dtp_w + (size_t)l*NF*8, dtp_b + l*NF,
        A_log + (size_t)l*NF*SD, hinit, Dv + l*NF,
        out_w + (size_t)l*NF*NF, out_b + l*NF, seq);
  }
  k_cross<<<CROSS_NBLK, 256, 0, stream>>>(seq, cb_w, cb_b, cb_ln_w, cb_ln_b, fin_ln_w, fin_ln_b, out);
}

// Round 6
// 1084.850 us; speedup vs baseline: 1.1774x; 1.1774x over previous
//
#include <hip/hip_runtime.h>
#include <math.h>

#define BKS 60      // B*K sequences
#define TL  1000    // T
#define NF  128     // N features
#define SD  12      // state dim S
#define RD  8       // dt rank
#define NCH 32      // scan chunks (last partial: 31*32=992, +8)
#define CLEN 32     // chunk length -> 38.4KB LDS
#define NTOK (BKS*TL)
#define MT  64      // GEMM token tile
#define NBLK ((NTOK + MT - 1)/MT)   // 938
#define XST 68      // xs [k][t] stride: (4k+t) banks -> <=2-way everywhere (free)
#define LNP 129     // cross_ln LDS stride

__device__ __forceinline__ float siluf(float x){ return x / (1.f + __expf(-x)); }
__device__ __forceinline__ float softplusf(float x){
  if (x > 20.f) return x;
  float e = __expf(x);
  return (x < -20.f) ? e : __logf(1.f + e);
}

// ---- K0: x (B,N,T,K) -> seq (B*K, T, N), one block per (b,t)
__global__ __launch_bounds__(256) void k_ingest(const float* __restrict__ x, float* __restrict__ seq){
  const int b = blockIdx.x / TL, t = blockIdx.x % TL;
  __shared__ float tile[30*NF];
  for (int e = threadIdx.x; e < 30*NF; e += 256){
    int n = e / 30, k = e - n*30;
    tile[k*NF + n] = x[((size_t)(b*NF + n)*TL + t)*30 + k];
  }
  __syncthreads();
  const size_t base = ((size_t)b*30)*TL*NF + (size_t)t*NF;
  for (int e = threadIdx.x; e < 30*NF; e += 256){
    int k = e >> 7, n = e & 127;
    seq[base + (size_t)k*TL*NF + n] = tile[e];
  }
}

// ---- K1 (R6): LayerNorm + in_proj, w FROM GLOBAL (L2), x in LDS [k][t] stride-68.
// Inner loop reads 128B LDS per 256 FMA (0.5 B/FLOP, was 1.0 -> LDS-pipe-bound at
// ~46% VALUBusy). One barrier total (was 17). LDS 34816 B.
__global__ __launch_bounds__(256) void k_ln_inproj(
    const float* __restrict__ seq, const float* __restrict__ lnw, const float* __restrict__ lnb,
    const float* __restrict__ iw, const float* __restrict__ ib,
    float* __restrict__ xcr, float* __restrict__ zb){
  __shared__ float xs[NF*XST];    // [k][t]
  const int tid = threadIdx.x;
  const int tok0 = blockIdx.x * MT;

  // P0: LN -> xs[n][t]
  {
    const int j = tid >> 4, l16 = tid & 15;
    for (int it = 0; it < 4; ++it){
      const int t = j + 16*it;
      const int tok = tok0 + t;
      float v[8]; float s = 0.f, s2 = 0.f;
      if (tok < NTOK){
        const float* sp = seq + (size_t)tok*NF;
        #pragma unroll
        for (int i = 0; i < 8; ++i){ float f = sp[l16 + 16*i]; v[i] = f; s += f; s2 += f*f; }
      } else {
        #pragma unroll
        for (int i = 0; i < 8; ++i) v[i] = 0.f;
      }
      #pragma unroll
      for (int m = 1; m < 16; m <<= 1){ s += __shfl_xor(s, m, 64); s2 += __shfl_xor(s2, m, 64); }
      const float mean = s * (1.f/128.f);
      const float rstd = rsqrtf(s2*(1.f/128.f) - mean*mean + 1e-5f);
      #pragma unroll
      for (int i = 0; i < 8; ++i){
        int n = l16 + 16*i;
        xs[n*XST + t] = (v[i]-mean)*rstd*lnw[n] + lnb[n];
      }
    }
  }
  __syncthreads();

  // P1: GEMM. og (tid>>3): outs og*8..+7 (rows 0..255 of iw; og>=16 -> z block);
  //           tg (tid&7): toks tg*8..+7.
  const int og = tid >> 3, tg = tid & 7;
  float acc[8][8];
  #pragma unroll
  for (int o = 0; o < 8; ++o)
    #pragma unroll
    for (int t = 0; t < 8; ++t) acc[o][t] = 0.f;
  const float* wbp = iw + (size_t)(og*8)*NF;
  for (int k4 = 0; k4 < 32; ++k4){
    const int kk = k4*4;
    float xv[4][8];
    #pragma unroll
    for (int q = 0; q < 4; ++q){
      const float4 a = *(const float4*)&xs[(kk+q)*XST + tg*8];
      const float4 b = *(const float4*)&xs[(kk+q)*XST + tg*8 + 4];
      xv[q][0]=a.x; xv[q][1]=a.y; xv[q][2]=a.z; xv[q][3]=a.w;
      xv[q][4]=b.x; xv[q][5]=b.y; xv[q][6]=b.z; xv[q][7]=b.w;
    }
    #pragma unroll
    for (int o = 0; o < 8; ++o){
      const float4 w4 = *(const float4*)(wbp + (size_t)o*NF + kk);
      const float wq[4] = {w4.x, w4.y, w4.z, w4.w};
      #pragma unroll
      for (int q = 0; q < 4; ++q)
        #pragma unroll
        for (int t = 0; t < 8; ++t)
          acc[o][t] = fmaf(wq[q], xv[q][t], acc[o][t]);
    }
  }

  float bo[8];
  #pragma unroll
  for (int i = 0; i < 8; ++i) bo[i] = ib[og*8 + i];   // og>=16 -> rows 128.. automatically
  float* outp = (og < 16) ? xcr : zb;
  const int ocol = (og < 16) ? og*8 : (og-16)*8;
  #pragma unroll
  for (int j = 0; j < 8; ++j){
    const int tok = tok0 + tg*8 + j;
    if (tok >= NTOK) break;
    float4 r0, r1;
    r0.x = acc[0][j]+bo[0]; r0.y = acc[1][j]+bo[1]; r0.z = acc[2][j]+bo[2]; r0.w = acc[3][j]+bo[3];
    r1.x = acc[4][j]+bo[4]; r1.y = acc[5][j]+bo[5]; r1.z = acc[6][j]+bo[6]; r1.w = acc[7][j]+bo[7];
    *(float4*)(outp + (size_t)tok*NF + ocol)     = r0;
    *(float4*)(outp + (size_t)tok*NF + ocol + 4) = r1;
  }
}

// ---- K2f (R1 known-good, 68.6us): conv+silu -> x-proj -> dt/B/C -> scan pass 1.
__global__ __launch_bounds__(256) void k_conv_scan1(
    const float* __restrict__ xcr,
    const float* __restrict__ cw, const float* __restrict__ cb,
    const float* __restrict__ xw, const float* __restrict__ dw, const float* __restrict__ db,
    const float* __restrict__ alog,
    float* __restrict__ xcc, float* __restrict__ dtb,
    float* __restrict__ Bmb, float* __restrict__ Cmb,
    float* __restrict__ ap, float* __restrict__ hfb){
  __shared__ float smem[9600];           // 38400 B
  float* sxr   = smem;                   // 4480 floats [r(35)][n]   (stage->conv)
  float* sdbc4 = smem;                   // 4096 floats [kq][t][o]   (xproj->reduce, aliases sxr)
  float* sdt   = smem;                   // 4096 floats [t][n]       (dt->scan, aliases sdbc4)
  float* sxc   = smem + 4480;            // 4096 floats [t][n]
  float* sdbc  = smem + 8576;            // 1024 floats [t][o32]
  const int bid = blockIdx.x;
  const int sq = bid / NCH, cblk = bid - sq*NCH;
  const int t0 = cblk*CLEN;
  const int lim = (TL - t0 < CLEN) ? (TL - t0) : CLEN;
  const int tid = threadIdx.x;

  // stage: 35 rows x 128 n as float4 (1120 slots)
  for (int i = 0; i < 5; ++i){
    const int e4 = tid + i*256;
    if (e4 < 35*32){
      const int r = e4 >> 5, n4 = (e4 & 31) << 2;
      const int t = t0 - 3 + r;
      float4 v = make_float4(0.f,0.f,0.f,0.f);
      if (t >= 0 && t < TL) v = *(const float4*)(xcr + ((size_t)sq*TL + t)*NF + n4);
      *(float4*)(sxr + r*NF + n4) = v;
    }
  }
  __syncthreads();

  // conv + silu -> sxc (b128) + xcc (global float4). 1024 slots of (r, n4).
  #pragma unroll
  for (int i = 0; i < 4; ++i){
    const int e4 = tid + i*256;
    const int r = e4 >> 5, n4 = (e4 & 31) << 2;
    const float4 c0 = *(const float4*)(cw + (size_t)(n4+0)*4);
    const float4 c1 = *(const float4*)(cw + (size_t)(n4+1)*4);
    const float4 c2 = *(const float4*)(cw + (size_t)(n4+2)*4);
    const float4 c3 = *(const float4*)(cw + (size_t)(n4+3)*4);
    const float4 x0 = *(const float4*)(sxr + (r+0)*NF + n4);
    const float4 x1 = *(const float4*)(sxr + (r+1)*NF + n4);
    const float4 x2 = *(const float4*)(sxr + (r+2)*NF + n4);
    const float4 x3 = *(const float4*)(sxr + (r+3)*NF + n4);
    float4 a = *(const float4*)(cb + n4);
    a.x = fmaf(x3.x, c0.w, fmaf(x2.x, c0.z, fmaf(x1.x, c0.y, fmaf(x0.x, c0.x, a.x))));
    a.y = fmaf(x3.y, c1.w, fmaf(x2.y, c1.z, fmaf(x1.y, c1.y, fmaf(x0.y, c1.x, a.y))));
    a.z = fmaf(x3.z, c2.w, fmaf(x2.z, c2.z, fmaf(x1.z, c2.y, fmaf(x0.z, c2.x, a.z))));
    a.w = fmaf(x3.w, c3.w, fmaf(x2.w, c3.z, fmaf(x1.w, c3.y, fmaf(x0.w, c3.x, a.w))));
    a.x = siluf(a.x); a.y = siluf(a.y); a.z = siluf(a.z); a.w = siluf(a.w);
    *(float4*)(sxc + r*NF + n4) = a;
    if (r < lim) *(float4*)(xcc + ((size_t)sq*TL + t0 + r)*NF + n4) = a;
  }
  __syncthreads();   // sxr reads done -> sdbc4 may overwrite; sxc visible

  // xproj: dbc[t][o] = xc[t][:] @ xw[o][:].  4o x 4t tile, K split 4 ways.
  {
    const int oq = tid & 7, tq = (tid >> 3) & 7, kq = tid >> 6;  // kq == wave id
    const int o0 = oq*4, tb = tq*4, k0 = kq*32;
    float acc[4][4];
    #pragma unroll
    for (int o = 0; o < 4; ++o)
      #pragma unroll
      for (int t = 0; t < 4; ++t) acc[o][t] = 0.f;
    #pragma unroll
    for (int k8 = 0; k8 < 8; ++k8){
      const int kk = k0 + k8*4;
      const float4 w0 = *(const float4*)(xw + (size_t)(o0+0)*NF + kk);
      const float4 w1 = *(const float4*)(xw + (size_t)(o0+1)*NF + kk);
      const float4 w2 = *(const float4*)(xw + (size_t)(o0+2)*NF + kk);
      const float4 w3 = *(const float4*)(xw + (size_t)(o0+3)*NF + kk);
      #pragma unroll
      for (int t = 0; t < 4; ++t){
        const float4 xv = *((const float4*)&sxc[(tb + t)*NF + kk]);
        acc[0][t] = fmaf(w0.w, xv.w, fmaf(w0.z, xv.z, fmaf(w0.y, xv.y, fmaf(w0.x, xv.x, acc[0][t]))));
        acc[1][t] = fmaf(w1.w, xv.w, fmaf(w1.z, xv.z, fmaf(w1.y, xv.y, fmaf(w1.x, xv.x, acc[1][t]))));
        acc[2][t] = fmaf(w2.w, xv.w, fmaf(w2.z, xv.z, fmaf(w2.y, xv.y, fmaf(w2.x, xv.x, acc[2][t]))));
        acc[3][t] = fmaf(w3.w, xv.w, fmaf(w3.z, xv.z, fmaf(w3.y, xv.y, fmaf(w3.x, xv.x, acc[3][t]))));
      }
    }
    #pragma unroll
    for (int t = 0; t < 4; ++t){
      float4 v = make_float4(acc[0][t], acc[1][t], acc[2][t], acc[3][t]);
      *(float4*)(sdbc4 + kq*1024 + (tb+t)*32 + o0) = v;
    }
  }
  __syncthreads();

  // reduce 4 K-partials -> sdbc[t][o]
  {
    const int o4 = (tid & 7) << 2, t = tid >> 3;
    float4 s0 = *(const float4*)(sdbc4 +          t*32 + o4);
    float4 s1 = *(const float4*)(sdbc4 + 1024 +   t*32 + o4);
    float4 s2 = *(const float4*)(sdbc4 + 2048 +   t*32 + o4);
    float4 s3 = *(const float4*)(sdbc4 + 3072 +   t*32 + o4);
    s0.x = (s0.x + s1.x) + (s2.x + s3.x);
    s0.y = (s0.y + s1.y) + (s2.y + s3.y);
    s0.z = (s0.z + s1.z) + (s2.z + s3.z);
    s0.w = (s0.w + s1.w) + (s2.w + s3.w);
    *(float4*)(sdbc + t*32 + o4) = s0;
  }
  __syncthreads();   // sdbc4 dead -> sdt may overwrite

  // dt = softplus(dbc[:, :8] @ dw^T + db)
  #pragma unroll
  for (int i = 0; i < 16; ++i){
    const int e = tid + i*256;
    const int r = e >> 7, n = e & 127;
    const float4 b0 = *(const float4*)(sdbc + r*32);
    const float4 b1 = *(const float4*)(sdbc + r*32 + 4);
    const float4 w0 = *(const float4*)(dw + (size_t)n*8);
    const float4 w1 = *(const float4*)(dw + (size_t)n*8 + 4);
    float acc = db[n];
    acc = fmaf(b0.x, w0.x, acc); acc = fmaf(b0.y, w0.y, acc);
    acc = fmaf(b0.z, w0.z, acc); acc = fmaf(b0.w, w0.w, acc);
    acc = fmaf(b1.x, w1.x, acc); acc = fmaf(b1.y, w1.y, acc);
    acc = fmaf(b1.z, w1.z, acc); acc = fmaf(b1.w, w1.w, acc);
    const float dtv = softplusf(acc);
    sdt[e] = dtv;
    if (e < lim*NF) dtb[((size_t)sq*TL + t0)*NF + e] = dtv;
  }
  // B/C global writes
  for (int e = tid; e < CLEN*2*SD; e += 256){
    int r = e / (2*SD), c = e - r*2*SD;
    if (r < lim){
      float v = sdbc[r*32 + 8 + c];
      size_t tok = (size_t)sq*TL + t0 + r;
      if (c < SD) Bmb[tok*SD + c] = v;
      else        Cmb[tok*SD + (c - SD)] = v;
    }
  }
  __syncthreads();

  // scan pass 1
  {
    const int n = tid & 127, p = tid >> 7;
    float Av[6], h[6];
    #pragma unroll
    for (int s = 0; s < 6; ++s){
      Av[s] = -__expf(alog[(size_t)n*SD + p*6 + s]);
      h[s] = 0.f;
    }
    float dts = 0.f;
    for (int tt = 0; tt < lim; ++tt){
      const float dtv = sdt[tt*NF + n];
      const float dx  = dtv * sxc[tt*NF + n];
      dts += dtv;
      float Bv[6];
      const float* br = sdbc + tt*32 + 8 + p*6;
      if (p == 0){
        const float4 a = *(const float4*)br;
        const float2 b = *(const float2*)(br + 4);
        Bv[0]=a.x; Bv[1]=a.y; Bv[2]=a.z; Bv[3]=a.w; Bv[4]=b.x; Bv[5]=b.y;
      } else {
        const float2 a = *(const float2*)br;
        const float4 b = *(const float4*)(br + 2);
        Bv[0]=a.x; Bv[1]=a.y; Bv[2]=b.x; Bv[3]=b.y; Bv[4]=b.z; Bv[5]=b.w;
      }
      #pragma unroll
      for (int s = 0; s < 6; ++s){
        const float dA = __expf(dtv*Av[s]);
        h[s] = fmaf(dA, h[s], dx*Bv[s]);
      }
    }
    const size_t base = (size_t)bid*SD*NF + n;
    #pragma unroll
    for (int s = 0; s < 6; ++s){
      ap [base + (p*6+s)*NF] = __expf(Av[s]*dts);
      hfb[base + (p*6+s)*NF] = h[s];
    }
  }
}

// ---- K3b: sequential combine across chunks
__global__ __launch_bounds__(128) void k_scan_combine(
    const float* __restrict__ ap, const float* __restrict__ hfb, float* __restrict__ hinit){
  const int sq = blockIdx.x;
  const int n = threadIdx.x;
  float h[SD];
  #pragma unroll
  for (int s = 0; s < SD; ++s) h[s] = 0.f;
  for (int c = 0; c < NCH; ++c){
    const size_t base = ((size_t)sq*NCH + c)*SD*NF + n;
    #pragma unroll
    for (int s = 0; s < SD; ++s){
      hinit[base + s*NF] = h[s];
      h[s] = fmaf(ap[base + s*NF], h[s], hfb[base + s*NF]);
    }
  }
}

// ---- K3c: scan pass 2 + gate: yb = (y + Dv*xc)*silu(z)
__global__ __launch_bounds__(128) void k_scan_pass2(
    const float* __restrict__ dtb, const float* __restrict__ xcc,
    const float* __restrict__ Bmb, const float* __restrict__ Cmb,
    const float* __restrict__ alog, const float* __restrict__ hinit,
    const float* __restrict__ zb, const float* __restrict__ Dv,
    float* __restrict__ yb){
  const int bid = blockIdx.x;
  const int sq = bid / NCH, c = bid - sq*NCH;
  const int t0 = c*CLEN;
  const int lim = (TL - t0 < CLEN) ? (TL - t0) : CLEN;
  const int n = threadIdx.x;
  const float4* A4 = (const float4*)(alog + (size_t)n*SD);
  float4 Aa = A4[0], Ab = A4[1], Ac = A4[2];
  float Av[SD] = {Aa.x,Aa.y,Aa.z,Aa.w, Ab.x,Ab.y,Ab.z,Ab.w, Ac.x,Ac.y,Ac.z,Ac.w};
  #pragma unroll
  for (int s = 0; s < SD; ++s) Av[s] = -__expf(Av[s]);
  const float dvn = Dv[n];
  float h[SD];
  const size_t hbase = (size_t)bid*SD*NF + n;
  #pragma unroll
  for (int s = 0; s < SD; ++s) h[s] = hinit[hbase + s*NF];
  const size_t tok0 = (size_t)sq*TL + t0;
  for (int tt = 0; tt < lim; ++tt){
    const size_t tok = tok0 + tt;
    float dtv = dtb[tok*NF + n];
    float xcv = xcc[tok*NF + n];
    float dx  = dtv * xcv;
    const float4* B4 = (const float4*)(Bmb + tok*SD);
    const float4* C4 = (const float4*)(Cmb + tok*SD);
    float4 Ba=B4[0], Bb=B4[1], Bc=B4[2];
    float4 Ca=C4[0], Cb=C4[1], Cc=C4[2];
    float Bv[SD] = {Ba.x,Ba.y,Ba.z,Ba.w, Bb.x,Bb.y,Bb.z,Bb.w, Bc.x,Bc.y,Bc.z,Bc.w};
    float Cv[SD] = {Ca.x,Ca.y,Ca.z,Ca.w, Cb.x,Cb.y,Cb.z,Cb.w, Cc.x,Cc.y,Cc.z,Cc.w};
    float yv = 0.f;
    #pragma unroll
    for (int s = 0; s < SD; ++s){
      float dA = __expf(dtv*Av[s]);
      h[s] = fmaf(dA, h[s], dx*Bv[s]);
      yv = fmaf(h[s], Cv[s], yv);
    }
    float zv = zb[tok*NF + n];
    yb[tok*NF + n] = fmaf(dvn, xcv, yv) * siluf(zv);
  }
}

// ---- K4 (R6): seq += yb @ ow^T + ob. w from global, x in LDS [n][t] stride-68.
// 16og x 16tg, acc[8][4]; 16B LDS per 128 FMA. One barrier.
__global__ __launch_bounds__(256) void k_gate_out(
    const float* __restrict__ yb,
    const float* __restrict__ ow, const float* __restrict__ ob,
    float* __restrict__ seq){
  __shared__ float xs[NF*XST];    // [n][t]
  const int tid = threadIdx.x;
  const int tok0 = blockIdx.x * MT;

  #pragma unroll
  for (int i = 0; i < 8; ++i){
    const int r  = (tid & 15) + ((i & 3) << 4);
    const int nq = (tid >> 4) + ((i >> 2) << 4);
    const int tok = tok0 + r;
    float4 v = make_float4(0.f,0.f,0.f,0.f);
    if (tok < NTOK) v = *(const float4*)(yb + (size_t)tok*NF + nq*4);
    xs[(nq*4+0)*XST + r] = v.x;
    xs[(nq*4+1)*XST + r] = v.y;
    xs[(nq*4+2)*XST + r] = v.z;
    xs[(nq*4+3)*XST + r] = v.w;
  }
  __syncthreads();

  const int og = tid >> 4, tg = tid & 15;   // 8 outs, 4 toks per thread
  float acc[8][4];
  #pragma unroll
  for (int o = 0; o < 8; ++o)
    #pragma unroll
    for (int j = 0; j < 4; ++j) acc[o][j] = 0.f;
  const float* owp = ow + (size_t)(og*8)*NF;
  for (int k4 = 0; k4 < 32; ++k4){
    const int kk = k4*4;
    float xv[4][4];
    #pragma unroll
    for (int q = 0; q < 4; ++q){
      const float4 a = *(const float4*)&xs[(kk+q)*XST + tg*4];
      xv[q][0]=a.x; xv[q][1]=a.y; xv[q][2]=a.z; xv[q][3]=a.w;
    }
    #pragma unroll
    for (int o = 0; o < 8; ++o){
      const float4 w4 = *(const float4*)(owp + (size_t)o*NF + kk);
      const float wq[4] = {w4.x, w4.y, w4.z, w4.w};
      #pragma unroll
      for (int q = 0; q < 4; ++q)
        #pragma unroll
        for (int j = 0; j < 4; ++j)
          acc[o][j] = fmaf(wq[q], xv[q][j], acc[o][j]);
    }
  }

  float bo[8];
  #pragma unroll
  for (int i = 0; i < 8; ++i) bo[i] = ob[og*8 + i];
  #pragma unroll
  for (int j = 0; j < 4; ++j){
    const int tok = tok0 + tg*4 + j;
    if (tok >= NTOK) break;
    float* dst = seq + (size_t)tok*NF + og*8;
    float4 s0 = *(float4*)dst;
    float4 s1 = *(float4*)(dst + 4);
    s0.x += acc[0][j]+bo[0]; s0.y += acc[1][j]+bo[1];
    s0.z += acc[2][j]+bo[2]; s0.w += acc[3][j]+bo[3];
    s1.x += acc[4][j]+bo[4]; s1.y += acc[5][j]+bo[5];
    s1.z += acc[6][j]+bo[6]; s1.w += acc[7][j]+bo[7];
    *(float4*)dst = s0;
    *(float4*)(dst + 4) = s1;
  }
}

// ---- K5a (R6): cross = main @ cb_w^T + cb_b. Same structure as k_gate_out; gather staging.
__global__ __launch_bounds__(256) void k_cross_gemm(
    const float* __restrict__ seq,
    const float* __restrict__ cbw, const float* __restrict__ cbb,
    float* __restrict__ cross){
  __shared__ float xs[NF*XST];    // [n][t]
  const int tid = threadIdx.x;
  const int tok0 = blockIdx.x * MT;

  #pragma unroll
  for (int i = 0; i < 8; ++i){
    const int r  = (tid & 15) + ((i & 3) << 4);
    const int nq = (tid >> 4) + ((i >> 2) << 4);
    const int tok = tok0 + r;
    float4 v = make_float4(0.f,0.f,0.f,0.f);
    if (tok < NTOK){
      int b = tok / 30000, rr = tok - b*30000;
      int t = rr / 30, k = rr - t*30;
      v = *(const float4*)(seq + ((size_t)(b*30 + k)*TL + t)*NF + nq*4);
    }
    xs[(nq*4+0)*XST + r] = v.x;
    xs[(nq*4+1)*XST + r] = v.y;
    xs[(nq*4+2)*XST + r] = v.z;
    xs[(nq*4+3)*XST + r] = v.w;
  }
  __syncthreads();

  const int og = tid >> 4, tg = tid & 15;
  float acc[8][4];
  #pragma unroll
  for (int o = 0; o < 8; ++o)
    #pragma unroll
    for (int j = 0; j < 4; ++j) acc[o][j] = 0.f;
  const float* wp = cbw + (size_t)(og*8)*NF;
  for (int k4 = 0; k4 < 32; ++k4){
    const int kk = k4*4;
    float xv[4][4];
    #pragma unroll
    for (int q = 0; q < 4; ++q){
      const float4 a = *(const float4*)&xs[(kk+q)*XST + tg*4];
      xv[q][0]=a.x; xv[q][1]=a.y; xv[q][2]=a.z; xv[q][3]=a.w;
    }
    #pragma unroll
    for (int o = 0; o < 8; ++o){
      const float4 w4 = *(const float4*)(wp + (size_t)o*NF + kk);
      const float wq[4] = {w4.x, w4.y, w4.z, w4.w};
      #pragma unroll
      for (int q = 0; q < 4; ++q)
        #pragma unroll
        for (int j = 0; j < 4; ++j)
          acc[o][j] = fmaf(wq[q], xv[q][j], acc[o][j]);
    }
  }

  float bo[8];
  #pragma unroll
  for (int i = 0; i < 8; ++i) bo[i] = cbb[og*8 + i];
  #pragma unroll
  for (int j = 0; j < 4; ++j){
    const int tok = tok0 + tg*4 + j;
    if (tok >= NTOK) break;
    float* dst = cross + (size_t)tok*NF + og*8;
    float4 s0, s1;
    s0.x = acc[0][j]+bo[0]; s0.y = acc[1][j]+bo[1];
    s0.z = acc[2][j]+bo[2]; s0.w = acc[3][j]+bo[3];
    s1.x = acc[4][j]+bo[4]; s1.y = acc[5][j]+bo[5];
    s1.z = acc[6][j]+bo[6]; s1.w = acc[7][j]+bo[7];
    *(float4*)dst = s0;
    *(float4*)(dst + 4) = s1;
  }
}

// ---- K5b: LN1 -> gelu -> +main -> LN2 -> transposed write. 32 tokens/block.
__global__ __launch_bounds__(256) void k_cross_ln(
    const float* __restrict__ seq, const float* __restrict__ cross,
    const float* __restrict__ clnw, const float* __restrict__ clnb,
    const float* __restrict__ flnw, const float* __restrict__ flnb,
    float* __restrict__ out){
  __shared__ float fs[32*LNP];
  const int tid = threadIdx.x;
  const int tok0 = blockIdx.x * 32;
  const int j16 = tid >> 4, l16 = tid & 15;

  for (int it = 0; it < 2; ++it){
    const int jj = j16 + 16*it;
    const int tok = tok0 + jj;
    const int b = tok / 30000, rr = tok - b*30000;
    const int t = rr / 30, k = rr - t*30;
    const float* cp = cross + (size_t)tok*NF;
    const float* mp = seq + ((size_t)(b*30 + k)*TL + t)*NF;
    float cv[8]; float s = 0.f, s2 = 0.f;
    #pragma unroll
    for (int i = 0; i < 8; ++i){
      float f = cp[l16 + 16*i]; cv[i] = f; s += f; s2 += f*f;
    }
    #pragma unroll
    for (int m = 1; m < 16; m <<= 1){ s += __shfl_xor(s, m, 64); s2 += __shfl_xor(s2, m, 64); }
    float mu = s * (1.f/128.f);
    float rs = rsqrtf(s2*(1.f/128.f) - mu*mu + 1e-5f);
    float rv[8]; float rsum = 0.f, rsum2 = 0.f;
    #pragma unroll
    for (int i = 0; i < 8; ++i){
      int n = l16 + 16*i;
      float cn = (cv[i] - mu)*rs*clnw[n] + clnb[n];
      float g = 0.5f*cn*(1.f + erff(cn*0.70710678118f));
      float res = mp[n] + g;
      rv[i] = res; rsum += res; rsum2 += res*res;
    }
    #pragma unroll
    for (int m = 1; m < 16; m <<= 1){ rsum += __shfl_xor(rsum, m, 64); rsum2 += __shfl_xor(rsum2, m, 64); }
    float mu2 = rsum * (1.f/128.f);
    float rs2 = rsqrtf(rsum2*(1.f/128.f) - mu2*mu2 + 1e-5f);
    #pragma unroll
    for (int i = 0; i < 8; ++i){
      int n = l16 + 16*i;
      fs[jj*LNP + n] = (rv[i] - mu2)*rs2*flnw[n] + flnb[n];
    }
  }
  __syncthreads();

  #pragma unroll
  for (int i = 0; i < 16; ++i){
    const int e = tid + i*256;
    const int j = e & 31, n = e >> 5;
    const int tok = tok0 + j;
    const int b = tok / 30000, rr = tok - b*30000;
    out[(size_t)(b*NF + n)*30000 + rr] = fs[j*LNP + n];
  }
}

extern "C" void kernel_launch(void* const* d_in, const int* in_sizes, int n_in,
                              void* d_out, int out_size, void* d_ws, size_t ws_size,
                              hipStream_t stream){
  const float* x       = (const float*)d_in[0];
  const float* ln_w    = (const float*)d_in[1];
  const float* ln_b    = (const float*)d_in[2];
  const float* in_w    = (const float*)d_in[3];
  const float* in_b    = (const float*)d_in[4];
  const float* conv_w  = (const float*)d_in[5];
  const float* conv_b  = (const float*)d_in[6];
  const float* xp_w    = (const float*)d_in[7];
  const float* dtp_w   = (const float*)d_in[8];
  const float* dtp_b   = (const float*)d_in[9];
  const float* A_log   = (const float*)d_in[10];
  const float* Dv      = (const float*)d_in[11];
  const float* out_w   = (const float*)d_in[12];
  const float* out_b   = (const float*)d_in[13];
  const float* cb_w    = (const float*)d_in[14];
  const float* cb_b    = (const float*)d_in[15];
  const float* cb_ln_w = (const float*)d_in[16];
  const float* cb_ln_b = (const float*)d_in[17];
  const float* fin_ln_w= (const float*)d_in[18];
  const float* fin_ln_b= (const float*)d_in[19];
  float* out = (float*)d_out;

  const size_t SEQSZ = (size_t)BKS*TL*NF;        // 7,680,000 floats
  const size_t CHSZ  = (size_t)BKS*NF*NCH*SD;    // 2,949,120 floats
  const size_t BASE  = 6*SEQSZ + 2*(size_t)BKS*TL*SD;   // ~190MB
  float* ws  = (float*)d_ws;
  float* seq = ws;
  float* xcr = ws + SEQSZ;
  float* zb  = ws + 2*SEQSZ;
  float* xcc = ws + 3*SEQSZ;
  float* dtb = ws + 4*SEQSZ;
  float* yb  = ws + 5*SEQSZ;
  float* Bmb = ws + 6*SEQSZ;
  float* Cmb = Bmb + (size_t)BKS*TL*SD;
  if (ws_size < BASE*sizeof(float)) return;

  // Liveness aliasing: ap/hfb -> yb region; hinit -> xcr; cross -> dtb.
  float* ap    = yb;
  float* hfb   = yb + CHSZ;
  float* hinit = xcr;
  float* cross = dtb;

  k_ingest<<<2*TL, 256, 0, stream>>>(x, seq);
  for (int l = 0; l < 4; ++l){
    k_ln_inproj<<<NBLK, 256, 0, stream>>>(seq, ln_w + l*NF, ln_b + l*NF,
        in_w + (size_t)l*2*NF*NF, in_b + l*2*NF, xcr, zb);
    k_conv_scan1<<<BKS*NCH, 256, 0, stream>>>(xcr, conv_w + (size_t)l*NF*4, conv_b + l*NF,
        xp_w + (size_t)l*32*NF, dtp_w + (size_t)l*NF*RD, dtp_b + l*NF,
        A_log + (size_t)l*NF*SD, xcc, dtb, Bmb, Cmb, ap, hfb);
    k_scan_combine<<<BKS, NF, 0, stream>>>(ap, hfb, hinit);
    k_scan_pass2<<<BKS*NCH, NF, 0, stream>>>(dtb, xcc, Bmb, Cmb, A_log + (size_t)l*NF*SD,
        hinit, zb, Dv + l*NF, yb);
    k_gate_out<<<NBLK, 256, 0, stream>>>(yb, out_w + (size_t)l*NF*NF, out_b + l*NF, seq);
  }
  k_cross_gemm<<<NBLK, 256, 0, stream>>>(seq, cb_w, cb_b, cross);
  k_cross_ln<<<NTOK/32, 256, 0, stream>>>(seq, cross, cb_ln_w, cb_ln_b, fin_ln_w, fin_ln_b, out);
}

// Round 7
// 863.422 us; speedup vs baseline: 1.4793x; 1.2565x over previous
//
#include <hip/hip_runtime.h>
#include <math.h>

#define BKS 60      // B*K sequences
#define TL  1000    // T
#define NF  128     // N features
#define SD  12      // state dim S
#define RD  8       // dt rank
#define NCH 32      // scan chunks
#define CLEN 32     // chunk length
#define NTOK (BKS*TL)
#define MT  64      // GEMM token tile
#define NBLK ((NTOK + MT - 1)/MT)   // 938
#define LNP 129     // cross_ln LDS stride
#define WCNT 212992 // bf16 weight pool: in_w 131072 + out_w 65536 + cb_w 16384

typedef __bf16 bf16x8 __attribute__((ext_vector_type(8)));
typedef float  f32x4  __attribute__((ext_vector_type(4)));

__device__ __forceinline__ float siluf(float x){ return x / (1.f + __expf(-x)); }
__device__ __forceinline__ float softplusf(float x){
  if (x > 20.f) return x;
  float e = __expf(x);
  return (x < -20.f) ? e : __logf(1.f + e);
}
__device__ __forceinline__ ushort bf16r(float f){          // RNE fp32->bf16
  uint u = __float_as_uint(f);
  return (ushort)((u + 0x7FFFu + ((u>>16)&1u)) >> 16);
}
__device__ __forceinline__ float bf2f(ushort h){ return __uint_as_float(((uint)h)<<16); }

// ---- K0: x (B,N,T,K) -> seq (B*K, T, N)
__global__ __launch_bounds__(256) void k_ingest(const float* __restrict__ x, float* __restrict__ seq){
  const int b = blockIdx.x / TL, t = blockIdx.x % TL;
  __shared__ float tile[30*NF];
  for (int e = threadIdx.x; e < 30*NF; e += 256){
    int n = e / 30, k = e - n*30;
    tile[k*NF + n] = x[((size_t)(b*NF + n)*TL + t)*30 + k];
  }
  __syncthreads();
  const size_t base = ((size_t)b*30)*TL*NF + (size_t)t*NF;
  for (int e = threadIdx.x; e < 30*NF; e += 256){
    int k = e >> 7, n = e & 127;
    seq[base + (size_t)k*TL*NF + n] = tile[e];
  }
}

// ---- KW: one-time fp32 -> bf16 (hi, lo) split of all GEMM weights
__global__ __launch_bounds__(256) void k_wconv(
    const float* __restrict__ iw, const float* __restrict__ ow, const float* __restrict__ cw,
    ushort* __restrict__ wh, ushort* __restrict__ wl){
  const int idx = blockIdx.x*256 + threadIdx.x;
  if (idx >= WCNT) return;
  float v;
  if (idx < 131072)      v = iw[idx];
  else if (idx < 196608) v = ow[idx - 131072];
  else                   v = cw[idx - 196608];
  const ushort h = bf16r(v);
  wh[idx] = h;
  wl[idx] = bf16r(v - bf2f(h));
}

// ---- K1 (R7): LayerNorm + in_proj via MFMA bf16x3 split.
// x: LN output split to bf16 hi/lo in LDS ([t][k], XOR swizzle (t&7)<<3 on half-index
// -> frag reads <=2-way). w: bf16 hi/lo from global (16B/lane contiguous).
// Per wave: 4 M-tiles x 4 N-tiles x 4 K-chunks x 3 mfma = 192 mfma. 1 barrier.
__global__ __launch_bounds__(256) void k_ln_inproj(
    const float* __restrict__ seq, const float* __restrict__ lnw, const float* __restrict__ lnb,
    const ushort* __restrict__ wh, const ushort* __restrict__ wl, const float* __restrict__ ib,
    float* __restrict__ xcr, float* __restrict__ zb){
  __shared__ short xsh[MT*NF];   // 16384 B
  __shared__ short xsl[MT*NF];   // 16384 B
  const int tid = threadIdx.x;
  const int tok0 = blockIdx.x * MT;

  // P0: LN -> bf16 split -> LDS
  {
    const int j = tid >> 4, l16 = tid & 15;
    for (int it = 0; it < 4; ++it){
      const int t = j + 16*it;
      const int tok = tok0 + t;
      float v[8]; float s = 0.f, s2 = 0.f;
      if (tok < NTOK){
        const float* sp = seq + (size_t)tok*NF;
        #pragma unroll
        for (int i = 0; i < 8; ++i){ float f = sp[l16 + 16*i]; v[i] = f; s += f; s2 += f*f; }
      } else {
        #pragma unroll
        for (int i = 0; i < 8; ++i) v[i] = 0.f;
      }
      #pragma unroll
      for (int m = 1; m < 16; m <<= 1){ s += __shfl_xor(s, m, 64); s2 += __shfl_xor(s2, m, 64); }
      const float mean = s * (1.f/128.f);
      const float rstd = rsqrtf(s2*(1.f/128.f) - mean*mean + 1e-5f);
      const int swz = (t & 7) << 3;
      #pragma unroll
      for (int i = 0; i < 8; ++i){
        const int n = l16 + 16*i;
        const float f = (v[i]-mean)*rstd*lnw[n] + lnb[n];
        const ushort h = bf16r(f);
        xsh[t*NF + (n ^ swz)] = (short)h;
        xsl[t*NF + (n ^ swz)] = (short)bf16r(f - bf2f(h));
      }
    }
  }
  __syncthreads();

  // P1: MFMA GEMM. wave w: outs w*64..w*64+63 (4 N-tiles), all 64 tokens (4 M-tiles).
  const int w = tid >> 6, lane = tid & 63;
  const int cl = lane & 15, q8 = (lane >> 4) * 8;
  const int obase = w * 64;
  f32x4 acc[4][4];
  #pragma unroll
  for (int m = 0; m < 4; ++m)
    #pragma unroll
    for (int nt = 0; nt < 4; ++nt) acc[m][nt] = (f32x4){0.f,0.f,0.f,0.f};

  for (int c = 0; c < 4; ++c){
    bf16x8 ah[4], al[4];
    #pragma unroll
    for (int m = 0; m < 4; ++m){
      const int r = m*16 + cl;
      const int hi = r*NF + ((c*32 + q8) ^ ((r & 7) << 3));
      ah[m] = *(const bf16x8*)&xsh[hi];
      al[m] = *(const bf16x8*)&xsl[hi];
    }
    #pragma unroll
    for (int nt = 0; nt < 4; ++nt){
      const int o = obase + nt*16 + cl;
      const size_t wo = (size_t)o*NF + c*32 + q8;
      const bf16x8 bh = *(const bf16x8*)(wh + wo);
      const bf16x8 bl = *(const bf16x8*)(wl + wo);
      #pragma unroll
      for (int m = 0; m < 4; ++m){
        acc[m][nt] = __builtin_amdgcn_mfma_f32_16x16x32_bf16(ah[m], bh, acc[m][nt], 0, 0, 0);
        acc[m][nt] = __builtin_amdgcn_mfma_f32_16x16x32_bf16(al[m], bh, acc[m][nt], 0, 0, 0);
        acc[m][nt] = __builtin_amdgcn_mfma_f32_16x16x32_bf16(ah[m], bl, acc[m][nt], 0, 0, 0);
      }
    }
  }

  // epilogue: D col=lane&15, row=(lane>>4)*4+reg
  const int rbase = (lane >> 4) * 4;
  #pragma unroll
  for (int nt = 0; nt < 4; ++nt){
    const int o = obase + nt*16 + cl;
    const float bias = ib[o];
    float* dst = (o < NF) ? xcr : zb;
    const int oc = (o < NF) ? o : (o - NF);
    #pragma unroll
    for (int m = 0; m < 4; ++m)
      #pragma unroll
      for (int j2 = 0; j2 < 4; ++j2){
        const int tok = tok0 + m*16 + rbase + j2;
        if (tok < NTOK) dst[(size_t)tok*NF + oc] = acc[m][nt][j2] + bias;
      }
  }
}

// ---- K2f (R1 known-good): conv+silu -> x-proj -> dt/B/C -> scan pass 1.
__global__ __launch_bounds__(256) void k_conv_scan1(
    const float* __restrict__ xcr,
    const float* __restrict__ cw, const float* __restrict__ cb,
    const float* __restrict__ xw, const float* __restrict__ dw, const float* __restrict__ db,
    const float* __restrict__ alog,
    float* __restrict__ xcc, float* __restrict__ dtb,
    float* __restrict__ Bmb, float* __restrict__ Cmb,
    float* __restrict__ ap, float* __restrict__ hfb){
  __shared__ float smem[9600];           // 38400 B
  float* sxr   = smem;
  float* sdbc4 = smem;
  float* sdt   = smem;
  float* sxc   = smem + 4480;
  float* sdbc  = smem + 8576;
  const int bid = blockIdx.x;
  const int sq = bid / NCH, cblk = bid - sq*NCH;
  const int t0 = cblk*CLEN;
  const int lim = (TL - t0 < CLEN) ? (TL - t0) : CLEN;
  const int tid = threadIdx.x;

  for (int i = 0; i < 5; ++i){
    const int e4 = tid + i*256;
    if (e4 < 35*32){
      const int r = e4 >> 5, n4 = (e4 & 31) << 2;
      const int t = t0 - 3 + r;
      float4 v = make_float4(0.f,0.f,0.f,0.f);
      if (t >= 0 && t < TL) v = *(const float4*)(xcr + ((size_t)sq*TL + t)*NF + n4);
      *(float4*)(sxr + r*NF + n4) = v;
    }
  }
  __syncthreads();

  #pragma unroll
  for (int i = 0; i < 4; ++i){
    const int e4 = tid + i*256;
    const int r = e4 >> 5, n4 = (e4 & 31) << 2;
    const float4 c0 = *(const float4*)(cw + (size_t)(n4+0)*4);
    const float4 c1 = *(const float4*)(cw + (size_t)(n4+1)*4);
    const float4 c2 = *(const float4*)(cw + (size_t)(n4+2)*4);
    const float4 c3 = *(const float4*)(cw + (size_t)(n4+3)*4);
    const float4 x0 = *(const float4*)(sxr + (r+0)*NF + n4);
    const float4 x1 = *(const float4*)(sxr + (r+1)*NF + n4);
    const float4 x2 = *(const float4*)(sxr + (r+2)*NF + n4);
    const float4 x3 = *(const float4*)(sxr + (r+3)*NF + n4);
    float4 a = *(const float4*)(cb + n4);
    a.x = fmaf(x3.x, c0.w, fmaf(x2.x, c0.z, fmaf(x1.x, c0.y, fmaf(x0.x, c0.x, a.x))));
    a.y = fmaf(x3.y, c1.w, fmaf(x2.y, c1.z, fmaf(x1.y, c1.y, fmaf(x0.y, c1.x, a.y))));
    a.z = fmaf(x3.z, c2.w, fmaf(x2.z, c2.z, fmaf(x1.z, c2.y, fmaf(x0.z, c2.x, a.z))));
    a.w = fmaf(x3.w, c3.w, fmaf(x2.w, c3.z, fmaf(x1.w, c3.y, fmaf(x0.w, c3.x, a.w))));
    a.x = siluf(a.x); a.y = siluf(a.y); a.z = siluf(a.z); a.w = siluf(a.w);
    *(float4*)(sxc + r*NF + n4) = a;
    if (r < lim) *(float4*)(xcc + ((size_t)sq*TL + t0 + r)*NF + n4) = a;
  }
  __syncthreads();

  {
    const int oq = tid & 7, tq = (tid >> 3) & 7, kq = tid >> 6;
    const int o0 = oq*4, tb = tq*4, k0 = kq*32;
    float acc[4][4];
    #pragma unroll
    for (int o = 0; o < 4; ++o)
      #pragma unroll
      for (int t = 0; t < 4; ++t) acc[o][t] = 0.f;
    #pragma unroll
    for (int k8 = 0; k8 < 8; ++k8){
      const int kk = k0 + k8*4;
      const float4 w0 = *(const float4*)(xw + (size_t)(o0+0)*NF + kk);
      const float4 w1 = *(const float4*)(xw + (size_t)(o0+1)*NF + kk);
      const float4 w2 = *(const float4*)(xw + (size_t)(o0+2)*NF + kk);
      const float4 w3 = *(const float4*)(xw + (size_t)(o0+3)*NF + kk);
      #pragma unroll
      for (int t = 0; t < 4; ++t){
        const float4 xv = *((const float4*)&sxc[(tb + t)*NF + kk]);
        acc[0][t] = fmaf(w0.w, xv.w, fmaf(w0.z, xv.z, fmaf(w0.y, xv.y, fmaf(w0.x, xv.x, acc[0][t]))));
        acc[1][t] = fmaf(w1.w, xv.w, fmaf(w1.z, xv.z, fmaf(w1.y, xv.y, fmaf(w1.x, xv.x, acc[1][t]))));
        acc[2][t] = fmaf(w2.w, xv.w, fmaf(w2.z, xv.z, fmaf(w2.y, xv.y, fmaf(w2.x, xv.x, acc[2][t]))));
        acc[3][t] = fmaf(w3.w, xv.w, fmaf(w3.z, xv.z, fmaf(w3.y, xv.y, fmaf(w3.x, xv.x, acc[3][t]))));
      }
    }
    #pragma unroll
    for (int t = 0; t < 4; ++t){
      float4 v = make_float4(acc[0][t], acc[1][t], acc[2][t], acc[3][t]);
      *(float4*)(sdbc4 + kq*1024 + (tb+t)*32 + o0) = v;
    }
  }
  __syncthreads();

  {
    const int o4 = (tid & 7) << 2, t = tid >> 3;
    float4 s0 = *(const float4*)(sdbc4 +          t*32 + o4);
    float4 s1 = *(const float4*)(sdbc4 + 1024 +   t*32 + o4);
    float4 s2 = *(const float4*)(sdbc4 + 2048 +   t*32 + o4);
    float4 s3 = *(const float4*)(sdbc4 + 3072 +   t*32 + o4);
    s0.x = (s0.x + s1.x) + (s2.x + s3.x);
    s0.y = (s0.y + s1.y) + (s2.y + s3.y);
    s0.z = (s0.z + s1.z) + (s2.z + s3.z);
    s0.w = (s0.w + s1.w) + (s2.w + s3.w);
    *(float4*)(sdbc + t*32 + o4) = s0;
  }
  __syncthreads();

  #pragma unroll
  for (int i = 0; i < 16; ++i){
    const int e = tid + i*256;
    const int r = e >> 7, n = e & 127;
    const float4 b0 = *(const float4*)(sdbc + r*32);
    const float4 b1 = *(const float4*)(sdbc + r*32 + 4);
    const float4 w0 = *(const float4*)(dw + (size_t)n*8);
    const float4 w1 = *(const float4*)(dw + (size_t)n*8 + 4);
    float acc = db[n];
    acc = fmaf(b0.x, w0.x, acc); acc = fmaf(b0.y, w0.y, acc);
    acc = fmaf(b0.z, w0.z, acc); acc = fmaf(b0.w, w0.w, acc);
    acc = fmaf(b1.x, w1.x, acc); acc = fmaf(b1.y, w1.y, acc);
    acc = fmaf(b1.z, w1.z, acc); acc = fmaf(b1.w, w1.w, acc);
    const float dtv = softplusf(acc);
    sdt[e] = dtv;
    if (e < lim*NF) dtb[((size_t)sq*TL + t0)*NF + e] = dtv;
  }
  for (int e = tid; e < CLEN*2*SD; e += 256){
    int r = e / (2*SD), c = e - r*2*SD;
    if (r < lim){
      float v = sdbc[r*32 + 8 + c];
      size_t tok = (size_t)sq*TL + t0 + r;
      if (c < SD) Bmb[tok*SD + c] = v;
      else        Cmb[tok*SD + (c - SD)] = v;
    }
  }
  __syncthreads();

  {
    const int n = tid & 127, p = tid >> 7;
    float Av[6], h[6];
    #pragma unroll
    for (int s = 0; s < 6; ++s){
      Av[s] = -__expf(alog[(size_t)n*SD + p*6 + s]);
      h[s] = 0.f;
    }
    float dts = 0.f;
    for (int tt = 0; tt < lim; ++tt){
      const float dtv = sdt[tt*NF + n];
      const float dx  = dtv * sxc[tt*NF + n];
      dts += dtv;
      float Bv[6];
      const float* br = sdbc + tt*32 + 8 + p*6;
      if (p == 0){
        const float4 a = *(const float4*)br;
        const float2 b = *(const float2*)(br + 4);
        Bv[0]=a.x; Bv[1]=a.y; Bv[2]=a.z; Bv[3]=a.w; Bv[4]=b.x; Bv[5]=b.y;
      } else {
        const float2 a = *(const float2*)br;
        const float4 b = *(const float4*)(br + 2);
        Bv[0]=a.x; Bv[1]=a.y; Bv[2]=b.x; Bv[3]=b.y; Bv[4]=b.z; Bv[5]=b.w;
      }
      #pragma unroll
      for (int s = 0; s < 6; ++s){
        const float dA = __expf(dtv*Av[s]);
        h[s] = fmaf(dA, h[s], dx*Bv[s]);
      }
    }
    const size_t base = (size_t)bid*SD*NF + n;
    #pragma unroll
    for (int s = 0; s < 6; ++s){
      ap [base + (p*6+s)*NF] = __expf(Av[s]*dts);
      hfb[base + (p*6+s)*NF] = h[s];
    }
  }
}

// ---- K3b: sequential combine across chunks
__global__ __launch_bounds__(128) void k_scan_combine(
    const float* __restrict__ ap, const float* __restrict__ hfb, float* __restrict__ hinit){
  const int sq = blockIdx.x;
  const int n = threadIdx.x;
  float h[SD];
  #pragma unroll
  for (int s = 0; s < SD; ++s) h[s] = 0.f;
  for (int c = 0; c < NCH; ++c){
    const size_t base = ((size_t)sq*NCH + c)*SD*NF + n;
    #pragma unroll
    for (int s = 0; s < SD; ++s){
      hinit[base + s*NF] = h[s];
      h[s] = fmaf(ap[base + s*NF], h[s], hfb[base + s*NF]);
    }
  }
}

// ---- K3c: scan pass 2 + gate
__global__ __launch_bounds__(128) void k_scan_pass2(
    const float* __restrict__ dtb, const float* __restrict__ xcc,
    const float* __restrict__ Bmb, const float* __restrict__ Cmb,
    const float* __restrict__ alog, const float* __restrict__ hinit,
    const float* __restrict__ zb, const float* __restrict__ Dv,
    float* __restrict__ yb){
  const int bid = blockIdx.x;
  const int sq = bid / NCH, c = bid - sq*NCH;
  const int t0 = c*CLEN;
  const int lim = (TL - t0 < CLEN) ? (TL - t0) : CLEN;
  const int n = threadIdx.x;
  const float4* A4 = (const float4*)(alog + (size_t)n*SD);
  float4 Aa = A4[0], Ab = A4[1], Ac = A4[2];
  float Av[SD] = {Aa.x,Aa.y,Aa.z,Aa.w, Ab.x,Ab.y,Ab.z,Ab.w, Ac.x,Ac.y,Ac.z,Ac.w};
  #pragma unroll
  for (int s = 0; s < SD; ++s) Av[s] = -__expf(Av[s]);
  const float dvn = Dv[n];
  float h[SD];
  const size_t hbase = (size_t)bid*SD*NF + n;
  #pragma unroll
  for (int s = 0; s < SD; ++s) h[s] = hinit[hbase + s*NF];
  const size_t tok0 = (size_t)sq*TL + t0;
  for (int tt = 0; tt < lim; ++tt){
    const size_t tok = tok0 + tt;
    float dtv = dtb[tok*NF + n];
    float xcv = xcc[tok*NF + n];
    float dx  = dtv * xcv;
    const float4* B4 = (const float4*)(Bmb + tok*SD);
    const float4* C4 = (const float4*)(Cmb + tok*SD);
    float4 Ba=B4[0], Bb=B4[1], Bc=B4[2];
    float4 Ca=C4[0], Cb=C4[1], Cc=C4[2];
    float Bv[SD] = {Ba.x,Ba.y,Ba.z,Ba.w, Bb.x,Bb.y,Bb.z,Bb.w, Bc.x,Bc.y,Bc.z,Bc.w};
    float Cv[SD] = {Ca.x,Ca.y,Ca.z,Ca.w, Cb.x,Cb.y,Cb.z,Cb.w, Cc.x,Cc.y,Cc.z,Cc.w};
    float yv = 0.f;
    #pragma unroll
    for (int s = 0; s < SD; ++s){
      float dA = __expf(dtv*Av[s]);
      h[s] = fmaf(dA, h[s], dx*Bv[s]);
      yv = fmaf(h[s], Cv[s], yv);
    }
    float zv = zb[tok*NF + n];
    yb[tok*NF + n] = fmaf(dvn, xcv, yv) * siluf(zv);
  }
}

// ---- K4 (R7): seq += yb @ ow^T + ob via MFMA bf16x3. Per wave: 4M x 2N x 4K x 3 = 96 mfma.
__global__ __launch_bounds__(256) void k_gate_out(
    const float* __restrict__ yb,
    const ushort* __restrict__ wh, const ushort* __restrict__ wl, const float* __restrict__ ob,
    float* __restrict__ seq){
  __shared__ short xsh[MT*NF];
  __shared__ short xsl[MT*NF];
  const int tid = threadIdx.x;
  const int tok0 = blockIdx.x * MT;

  #pragma unroll
  for (int i = 0; i < 8; ++i){
    const int r  = (tid & 15) + ((i & 3) << 4);
    const int nq = (tid >> 4) + ((i >> 2) << 4);
    const int tok = tok0 + r;
    float4 v = make_float4(0.f,0.f,0.f,0.f);
    if (tok < NTOK) v = *(const float4*)(yb + (size_t)tok*NF + nq*4);
    const ushort h0 = bf16r(v.x), h1 = bf16r(v.y), h2 = bf16r(v.z), h3 = bf16r(v.w);
    const ushort l0 = bf16r(v.x - bf2f(h0)), l1 = bf16r(v.y - bf2f(h1));
    const ushort l2 = bf16r(v.z - bf2f(h2)), l3 = bf16r(v.w - bf2f(h3));
    const int hi = r*NF + ((nq*4) ^ ((r & 7) << 3));
    *(uint2*)&xsh[hi] = make_uint2((uint)h0 | ((uint)h1 << 16), (uint)h2 | ((uint)h3 << 16));
    *(uint2*)&xsl[hi] = make_uint2((uint)l0 | ((uint)l1 << 16), (uint)l2 | ((uint)l3 << 16));
  }
  __syncthreads();

  const int w = tid >> 6, lane = tid & 63;
  const int cl = lane & 15, q8 = (lane >> 4) * 8;
  const int obase = w * 32;
  f32x4 acc[4][2];
  #pragma unroll
  for (int m = 0; m < 4; ++m)
    #pragma unroll
    for (int nt = 0; nt < 2; ++nt) acc[m][nt] = (f32x4){0.f,0.f,0.f,0.f};

  for (int c = 0; c < 4; ++c){
    bf16x8 ah[4], al[4];
    #pragma unroll
    for (int m = 0; m < 4; ++m){
      const int r = m*16 + cl;
      const int hi = r*NF + ((c*32 + q8) ^ ((r & 7) << 3));
      ah[m] = *(const bf16x8*)&xsh[hi];
      al[m] = *(const bf16x8*)&xsl[hi];
    }
    #pragma unroll
    for (int nt = 0; nt < 2; ++nt){
      const int o = obase + nt*16 + cl;
      const size_t wo = (size_t)o*NF + c*32 + q8;
      const bf16x8 bh = *(const bf16x8*)(wh + wo);
      const bf16x8 bl = *(const bf16x8*)(wl + wo);
      #pragma unroll
      for (int m = 0; m < 4; ++m){
        acc[m][nt] = __builtin_amdgcn_mfma_f32_16x16x32_bf16(ah[m], bh, acc[m][nt], 0, 0, 0);
        acc[m][nt] = __builtin_amdgcn_mfma_f32_16x16x32_bf16(al[m], bh, acc[m][nt], 0, 0, 0);
        acc[m][nt] = __builtin_amdgcn_mfma_f32_16x16x32_bf16(ah[m], bl, acc[m][nt], 0, 0, 0);
      }
    }
  }

  const int rbase = (lane >> 4) * 4;
  #pragma unroll
  for (int nt = 0; nt < 2; ++nt){
    const int o = obase + nt*16 + cl;
    const float bias = ob[o];
    #pragma unroll
    for (int m = 0; m < 4; ++m)
      #pragma unroll
      for (int j2 = 0; j2 < 4; ++j2){
        const int tok = tok0 + m*16 + rbase + j2;
        if (tok < NTOK){
          float* dst = seq + (size_t)tok*NF + o;
          *dst = *dst + acc[m][nt][j2] + bias;
        }
      }
  }
}

// ---- K5a (R7): cross = main @ cb_w^T + cb_b via MFMA bf16x3; gather staging.
__global__ __launch_bounds__(256) void k_cross_gemm(
    const float* __restrict__ seq,
    const ushort* __restrict__ wh, const ushort* __restrict__ wl, const float* __restrict__ cbb,
    float* __restrict__ cross){
  __shared__ short xsh[MT*NF];
  __shared__ short xsl[MT*NF];
  const int tid = threadIdx.x;
  const int tok0 = blockIdx.x * MT;

  #pragma unroll
  for (int i = 0; i < 8; ++i){
    const int r  = (tid & 15) + ((i & 3) << 4);
    const int nq = (tid >> 4) + ((i >> 2) << 4);
    const int tok = tok0 + r;
    float4 v = make_float4(0.f,0.f,0.f,0.f);
    if (tok < NTOK){
      int b = tok / 30000, rr = tok - b*30000;
      int t = rr / 30, k = rr - t*30;
      v = *(const float4*)(seq + ((size_t)(b*30 + k)*TL + t)*NF + nq*4);
    }
    const ushort h0 = bf16r(v.x), h1 = bf16r(v.y), h2 = bf16r(v.z), h3 = bf16r(v.w);
    const ushort l0 = bf16r(v.x - bf2f(h0)), l1 = bf16r(v.y - bf2f(h1));
    const ushort l2 = bf16r(v.z - bf2f(h2)), l3 = bf16r(v.w - bf2f(h3));
    const int hi = r*NF + ((nq*4) ^ ((r & 7) << 3));
    *(uint2*)&xsh[hi] = make_uint2((uint)h0 | ((uint)h1 << 16), (uint)h2 | ((uint)h3 << 16));
    *(uint2*)&xsl[hi] = make_uint2((uint)l0 | ((uint)l1 << 16), (uint)l2 | ((uint)l3 << 16));
  }
  __syncthreads();

  const int w = tid >> 6, lane = tid & 63;
  const int cl = lane & 15, q8 = (lane >> 4) * 8;
  const int obase = w * 32;
  f32x4 acc[4][2];
  #pragma unroll
  for (int m = 0; m < 4; ++m)
    #pragma unroll
    for (int nt = 0; nt < 2; ++nt) acc[m][nt] = (f32x4){0.f,0.f,0.f,0.f};

  for (int c = 0; c < 4; ++c){
    bf16x8 ah[4], al[4];
    #pragma unroll
    for (int m = 0; m < 4; ++m){
      const int r = m*16 + cl;
      const int hi = r*NF + ((c*32 + q8) ^ ((r & 7) << 3));
      ah[m] = *(const bf16x8*)&xsh[hi];
      al[m] = *(const bf16x8*)&xsl[hi];
    }
    #pragma unroll
    for (int nt = 0; nt < 2; ++nt){
      const int o = obase + nt*16 + cl;
      const size_t wo = (size_t)o*NF + c*32 + q8;
      const bf16x8 bh = *(const bf16x8*)(wh + wo);
      const bf16x8 bl = *(const bf16x8*)(wl + wo);
      #pragma unroll
      for (int m = 0; m < 4; ++m){
        acc[m][nt] = __builtin_amdgcn_mfma_f32_16x16x32_bf16(ah[m], bh, acc[m][nt], 0, 0, 0);
        acc[m][nt] = __builtin_amdgcn_mfma_f32_16x16x32_bf16(al[m], bh, acc[m][nt], 0, 0, 0);
        acc[m][nt] = __builtin_amdgcn_mfma_f32_16x16x32_bf16(ah[m], bl, acc[m][nt], 0, 0, 0);
      }
    }
  }

  const int rbase = (lane >> 4) * 4;
  #pragma unroll
  for (int nt = 0; nt < 2; ++nt){
    const int o = obase + nt*16 + cl;
    const float bias = cbb[o];
    #pragma unroll
    for (int m = 0; m < 4; ++m)
      #pragma unroll
      for (int j2 = 0; j2 < 4; ++j2){
        const int tok = tok0 + m*16 + rbase + j2;
        if (tok < NTOK) cross[(size_t)tok*NF + o] = acc[m][nt][j2] + bias;
      }
  }
}

// ---- K5b: LN1 -> gelu -> +main -> LN2 -> transposed write. 32 tokens/block.
__global__ __launch_bounds__(256) void k_cross_ln(
    const float* __restrict__ seq, const float* __restrict__ cross,
    const float* __restrict__ clnw, const float* __restrict__ clnb,
    const float* __restrict__ flnw, const float* __restrict__ flnb,
    float* __restrict__ out){
  __shared__ float fs[32*LNP];
  const int tid = threadIdx.x;
  const int tok0 = blockIdx.x * 32;
  const int j16 = tid >> 4, l16 = tid & 15;

  for (int it = 0; it < 2; ++it){
    const int jj = j16 + 16*it;
    const int tok = tok0 + jj;
    const int b = tok / 30000, rr = tok - b*30000;
    const int t = rr / 30, k = rr - t*30;
    const float* cp = cross + (size_t)tok*NF;
    const float* mp = seq + ((size_t)(b*30 + k)*TL + t)*NF;
    float cv[8]; float s = 0.f, s2 = 0.f;
    #pragma unroll
    for (int i = 0; i < 8; ++i){
      float f = cp[l16 + 16*i]; cv[i] = f; s += f; s2 += f*f;
    }
    #pragma unroll
    for (int m = 1; m < 16; m <<= 1){ s += __shfl_xor(s, m, 64); s2 += __shfl_xor(s2, m, 64); }
    float mu = s * (1.f/128.f);
    float rs = rsqrtf(s2*(1.f/128.f) - mu*mu + 1e-5f);
    float rv[8]; float rsum = 0.f, rsum2 = 0.f;
    #pragma unroll
    for (int i = 0; i < 8; ++i){
      int n = l16 + 16*i;
      float cn = (cv[i] - mu)*rs*clnw[n] + clnb[n];
      float g = 0.5f*cn*(1.f + erff(cn*0.70710678118f));
      float res = mp[n] + g;
      rv[i] = res; rsum += res; rsum2 += res*res;
    }
    #pragma unroll
    for (int m = 1; m < 16; m <<= 1){ rsum += __shfl_xor(rsum, m, 64); rsum2 += __shfl_xor(rsum2, m, 64); }
    float mu2 = rsum * (1.f/128.f);
    float rs2 = rsqrtf(rsum2*(1.f/128.f) - mu2*mu2 + 1e-5f);
    #pragma unroll
    for (int i = 0; i < 8; ++i){
      int n = l16 + 16*i;
      fs[jj*LNP + n] = (rv[i] - mu2)*rs2*flnw[n] + flnb[n];
    }
  }
  __syncthreads();

  #pragma unroll
  for (int i = 0; i < 16; ++i){
    const int e = tid + i*256;
    const int j = e & 31, n = e >> 5;
    const int tok = tok0 + j;
    const int b = tok / 30000, rr = tok - b*30000;
    out[(size_t)(b*NF + n)*30000 + rr] = fs[j*LNP + n];
  }
}

extern "C" void kernel_launch(void* const* d_in, const int* in_sizes, int n_in,
                              void* d_out, int out_size, void* d_ws, size_t ws_size,
                              hipStream_t stream){
  const float* x       = (const float*)d_in[0];
  const float* ln_w    = (const float*)d_in[1];
  const float* ln_b    = (const float*)d_in[2];
  const float* in_w    = (const float*)d_in[3];
  const float* in_b    = (const float*)d_in[4];
  const float* conv_w  = (const float*)d_in[5];
  const float* conv_b  = (const float*)d_in[6];
  const float* xp_w    = (const float*)d_in[7];
  const float* dtp_w   = (const float*)d_in[8];
  const float* dtp_b   = (const float*)d_in[9];
  const float* A_log   = (const float*)d_in[10];
  const float* Dv      = (const float*)d_in[11];
  const float* out_w   = (const float*)d_in[12];
  const float* out_b   = (const float*)d_in[13];
  const float* cb_w    = (const float*)d_in[14];
  const float* cb_b    = (const float*)d_in[15];
  const float* cb_ln_w = (const float*)d_in[16];
  const float* cb_ln_b = (const float*)d_in[17];
  const float* fin_ln_w= (const float*)d_in[18];
  const float* fin_ln_b= (const float*)d_in[19];
  float* out = (float*)d_out;

  const size_t SEQSZ = (size_t)BKS*TL*NF;        // 7,680,000 floats
  const size_t CHSZ  = (size_t)BKS*NF*NCH*SD;    // 2,949,120 floats
  const size_t FBASE = 6*SEQSZ + 2*(size_t)BKS*TL*SD;   // fp32 region
  const size_t BASE  = FBASE + WCNT;                    // + bf16 weight pool (2*WCNT ushorts)
  float* ws  = (float*)d_ws;
  float* seq = ws;
  float* xcr = ws + SEQSZ;
  float* zb  = ws + 2*SEQSZ;
  float* xcc = ws + 3*SEQSZ;
  float* dtb = ws + 4*SEQSZ;
  float* yb  = ws + 5*SEQSZ;
  float* Bmb = ws + 6*SEQSZ;
  float* Cmb = Bmb + (size_t)BKS*TL*SD;
  ushort* wbh = (ushort*)(ws + FBASE);
  ushort* wbl = wbh + WCNT;
  if (ws_size < BASE*sizeof(float)) return;

  // Liveness aliasing: ap/hfb -> yb region; hinit -> xcr; cross -> dtb.
  float* ap    = yb;
  float* hfb   = yb + CHSZ;
  float* hinit = xcr;
  float* cross = dtb;

  k_wconv<<<(WCNT + 255)/256, 256, 0, stream>>>(in_w, out_w, cb_w, wbh, wbl);
  k_ingest<<<2*TL, 256, 0, stream>>>(x, seq);
  for (int l = 0; l < 4; ++l){
    k_ln_inproj<<<NBLK, 256, 0, stream>>>(seq, ln_w + l*NF, ln_b + l*NF,
        wbh + (size_t)l*32768, wbl + (size_t)l*32768, in_b + l*2*NF, xcr, zb);
    k_conv_scan1<<<BKS*NCH, 256, 0, stream>>>(xcr, conv_w + (size_t)l*NF*4, conv_b + l*NF,
        xp_w + (size_t)l*32*NF, dtp_w + (size_t)l*NF*RD, dtp_b + l*NF,
        A_log + (size_t)l*NF*SD, xcc, dtb, Bmb, Cmb, ap, hfb);
    k_scan_combine<<<BKS, NF, 0, stream>>>(ap, hfb, hinit);
    k_scan_pass2<<<BKS*NCH, NF, 0, stream>>>(dtb, xcc, Bmb, Cmb, A_log + (size_t)l*NF*SD,
        hinit, zb, Dv + l*NF, yb);
    k_gate_out<<<NBLK, 256, 0, stream>>>(yb,
        wbh + 131072 + (size_t)l*16384, wbl + 131072 + (size_t)l*16384, out_b + l*NF, seq);
  }
  k_cross_gemm<<<NBLK, 256, 0, stream>>>(seq, wbh + 196608, wbl + 196608, cb_b, cross);
  k_cross_ln<<<NTOK/32, 256, 0, stream>>>(seq, cross, cb_ln_w, cb_ln_b, fin_ln_w, fin_ln_b, out);
}

// Round 8
// 740.634 us; speedup vs baseline: 1.7246x; 1.1658x over previous
//
#include <hip/hip_runtime.h>
#include <math.h>

#define BKS 60      // B*K sequences
#define TL  1000    // T
#define NF  128     // N features
#define SD  12      // state dim S
#define RD  8       // dt rank
#define NCH 32      // scan chunks
#define CLEN 32     // chunk length
#define NTOK (BKS*TL)
#define MT  64      // GEMM token tile
#define NBLK ((NTOK + MT - 1)/MT)   // 938
#define LNP 129     // cross_ln LDS stride
// bf16 weight pool: in_w 131072 | out_w 65536 | cb_w 16384 | xp_w 16384
#define OFF_OW  131072
#define OFF_CBW 196608
#define OFF_XW  212992
#define WCNT    229376

typedef __bf16 bf16x8 __attribute__((ext_vector_type(8)));
typedef float  f32x4  __attribute__((ext_vector_type(4)));

__device__ __forceinline__ float siluf(float x){ return x / (1.f + __expf(-x)); }
__device__ __forceinline__ float softplusf(float x){
  if (x > 20.f) return x;
  float e = __expf(x);
  return (x < -20.f) ? e : __logf(1.f + e);
}
__device__ __forceinline__ ushort bf16r(float f){          // RNE fp32->bf16
  uint u = __float_as_uint(f);
  return (ushort)((u + 0x7FFFu + ((u>>16)&1u)) >> 16);
}
__device__ __forceinline__ float bf2f(ushort h){ return __uint_as_float(((uint)h)<<16); }

// ---- K0: x (B,N,T,K) -> seq (B*K, T, N)
__global__ __launch_bounds__(256) void k_ingest(const float* __restrict__ x, float* __restrict__ seq){
  const int b = blockIdx.x / TL, t = blockIdx.x % TL;
  __shared__ float tile[30*NF];
  for (int e = threadIdx.x; e < 30*NF; e += 256){
    int n = e / 30, k = e - n*30;
    tile[k*NF + n] = x[((size_t)(b*NF + n)*TL + t)*30 + k];
  }
  __syncthreads();
  const size_t base = ((size_t)b*30)*TL*NF + (size_t)t*NF;
  for (int e = threadIdx.x; e < 30*NF; e += 256){
    int k = e >> 7, n = e & 127;
    seq[base + (size_t)k*TL*NF + n] = tile[e];
  }
}

// ---- KW: one-time fp32 -> bf16 (hi, lo) split of all GEMM weights (+ xp_w now)
__global__ __launch_bounds__(256) void k_wconv(
    const float* __restrict__ iw, const float* __restrict__ ow,
    const float* __restrict__ cw, const float* __restrict__ xw,
    ushort* __restrict__ wh, ushort* __restrict__ wl){
  const int idx = blockIdx.x*256 + threadIdx.x;
  if (idx >= WCNT) return;
  float v;
  if (idx < OFF_OW)       v = iw[idx];
  else if (idx < OFF_CBW) v = ow[idx - OFF_OW];
  else if (idx < OFF_XW)  v = cw[idx - OFF_CBW];
  else                    v = xw[idx - OFF_XW];
  const ushort h = bf16r(v);
  wh[idx] = h;
  wl[idx] = bf16r(v - bf2f(h));
}

// ---- K1 (R7 known-good): LayerNorm + in_proj via MFMA bf16x3 split.
__global__ __launch_bounds__(256) void k_ln_inproj(
    const float* __restrict__ seq, const float* __restrict__ lnw, const float* __restrict__ lnb,
    const ushort* __restrict__ wh, const ushort* __restrict__ wl, const float* __restrict__ ib,
    float* __restrict__ xcr, float* __restrict__ zb){
  __shared__ short xsh[MT*NF];   // 16384 B
  __shared__ short xsl[MT*NF];   // 16384 B
  const int tid = threadIdx.x;
  const int tok0 = blockIdx.x * MT;

  {
    const int j = tid >> 4, l16 = tid & 15;
    for (int it = 0; it < 4; ++it){
      const int t = j + 16*it;
      const int tok = tok0 + t;
      float v[8]; float s = 0.f, s2 = 0.f;
      if (tok < NTOK){
        const float* sp = seq + (size_t)tok*NF;
        #pragma unroll
        for (int i = 0; i < 8; ++i){ float f = sp[l16 + 16*i]; v[i] = f; s += f; s2 += f*f; }
      } else {
        #pragma unroll
        for (int i = 0; i < 8; ++i) v[i] = 0.f;
      }
      #pragma unroll
      for (int m = 1; m < 16; m <<= 1){ s += __shfl_xor(s, m, 64); s2 += __shfl_xor(s2, m, 64); }
      const float mean = s * (1.f/128.f);
      const float rstd = rsqrtf(s2*(1.f/128.f) - mean*mean + 1e-5f);
      const int swz = (t & 7) << 3;
      #pragma unroll
      for (int i = 0; i < 8; ++i){
        const int n = l16 + 16*i;
        const float f = (v[i]-mean)*rstd*lnw[n] + lnb[n];
        const ushort h = bf16r(f);
        xsh[t*NF + (n ^ swz)] = (short)h;
        xsl[t*NF + (n ^ swz)] = (short)bf16r(f - bf2f(h));
      }
    }
  }
  __syncthreads();

  const int w = tid >> 6, lane = tid & 63;
  const int cl = lane & 15, q8 = (lane >> 4) * 8;
  const int obase = w * 64;
  f32x4 acc[4][4];
  #pragma unroll
  for (int m = 0; m < 4; ++m)
    #pragma unroll
    for (int nt = 0; nt < 4; ++nt) acc[m][nt] = (f32x4){0.f,0.f,0.f,0.f};

  for (int c = 0; c < 4; ++c){
    bf16x8 ah[4], al[4];
    #pragma unroll
    for (int m = 0; m < 4; ++m){
      const int r = m*16 + cl;
      const int hi = r*NF + ((c*32 + q8) ^ ((r & 7) << 3));
      ah[m] = *(const bf16x8*)&xsh[hi];
      al[m] = *(const bf16x8*)&xsl[hi];
    }
    #pragma unroll
    for (int nt = 0; nt < 4; ++nt){
      const int o = obase + nt*16 + cl;
      const size_t wo = (size_t)o*NF + c*32 + q8;
      const bf16x8 bh = *(const bf16x8*)(wh + wo);
      const bf16x8 bl = *(const bf16x8*)(wl + wo);
      #pragma unroll
      for (int m = 0; m < 4; ++m){
        acc[m][nt] = __builtin_amdgcn_mfma_f32_16x16x32_bf16(ah[m], bh, acc[m][nt], 0, 0, 0);
        acc[m][nt] = __builtin_amdgcn_mfma_f32_16x16x32_bf16(al[m], bh, acc[m][nt], 0, 0, 0);
        acc[m][nt] = __builtin_amdgcn_mfma_f32_16x16x32_bf16(ah[m], bl, acc[m][nt], 0, 0, 0);
      }
    }
  }

  const int rbase = (lane >> 4) * 4;
  #pragma unroll
  for (int nt = 0; nt < 4; ++nt){
    const int o = obase + nt*16 + cl;
    const float bias = ib[o];
    float* dst = (o < NF) ? xcr : zb;
    const int oc = (o < NF) ? o : (o - NF);
    #pragma unroll
    for (int m = 0; m < 4; ++m)
      #pragma unroll
      for (int j2 = 0; j2 < 4; ++j2){
        const int tok = tok0 + m*16 + rbase + j2;
        if (tok < NTOK) dst[(size_t)tok*NF + oc] = acc[m][nt][j2] + bias;
      }
  }
}

// ---- K2f (R8): conv+silu (bf16-split out) -> MFMA xproj -> dt -> scan pass 1
// (power-trick dA: Av[s] == -(s+1) for this model => dA = exp(-dt)^(s+1); guarded
// runtime check with exact-exp fallback). LDS: sxr/sdt 17920 | xch 8192 | xcl 8192
// | sdbc 4096 = 38400 B.
__global__ __launch_bounds__(256) void k_conv_scan1(
    const float* __restrict__ xcr,
    const float* __restrict__ cw, const float* __restrict__ cb,
    const ushort* __restrict__ xwh, const ushort* __restrict__ xwl,
    const float* __restrict__ dw, const float* __restrict__ db,
    const float* __restrict__ alog,
    float* __restrict__ xcc, float* __restrict__ dtb,
    float* __restrict__ Bmb, float* __restrict__ Cmb,
    float* __restrict__ ap, float* __restrict__ hfb){
  __shared__ float smem[9600];                 // 38400 B
  float* sxr  = smem;                          // [35][128] f32 (stage->conv)
  float* sdt  = smem;                          // [32][128] f32 (dt->scan, aliases sxr)
  short* xch  = (short*)(smem + 4480);         // [32*128] bf16 hi (swizzled)
  short* xcl  = (short*)(smem + 6528);         // [32*128] bf16 lo
  float* sdbc = smem + 8576;                   // [32][32]
  const int bid = blockIdx.x;
  const int sq = bid / NCH, cblk = bid - sq*NCH;
  const int t0 = cblk*CLEN;
  const int lim = (TL - t0 < CLEN) ? (TL - t0) : CLEN;
  const int tid = threadIdx.x;

  // stage: 35 rows x 128 n as float4
  for (int i = 0; i < 5; ++i){
    const int e4 = tid + i*256;
    if (e4 < 35*32){
      const int r = e4 >> 5, n4 = (e4 & 31) << 2;
      const int t = t0 - 3 + r;
      float4 v = make_float4(0.f,0.f,0.f,0.f);
      if (t >= 0 && t < TL) v = *(const float4*)(xcr + ((size_t)sq*TL + t)*NF + n4);
      *(float4*)(sxr + r*NF + n4) = v;
    }
  }
  __syncthreads();

  // conv + silu -> bf16 hi/lo LDS (swizzled) + xcc global f32
  #pragma unroll
  for (int i = 0; i < 4; ++i){
    const int e4 = tid + i*256;
    const int r = e4 >> 5, n4 = (e4 & 31) << 2;
    const float4 c0 = *(const float4*)(cw + (size_t)(n4+0)*4);
    const float4 c1 = *(const float4*)(cw + (size_t)(n4+1)*4);
    const float4 c2 = *(const float4*)(cw + (size_t)(n4+2)*4);
    const float4 c3 = *(const float4*)(cw + (size_t)(n4+3)*4);
    const float4 x0 = *(const float4*)(sxr + (r+0)*NF + n4);
    const float4 x1 = *(const float4*)(sxr + (r+1)*NF + n4);
    const float4 x2 = *(const float4*)(sxr + (r+2)*NF + n4);
    const float4 x3 = *(const float4*)(sxr + (r+3)*NF + n4);
    float4 a = *(const float4*)(cb + n4);
    a.x = fmaf(x3.x, c0.w, fmaf(x2.x, c0.z, fmaf(x1.x, c0.y, fmaf(x0.x, c0.x, a.x))));
    a.y = fmaf(x3.y, c1.w, fmaf(x2.y, c1.z, fmaf(x1.y, c1.y, fmaf(x0.y, c1.x, a.y))));
    a.z = fmaf(x3.z, c2.w, fmaf(x2.z, c2.z, fmaf(x1.z, c2.y, fmaf(x0.z, c2.x, a.z))));
    a.w = fmaf(x3.w, c3.w, fmaf(x2.w, c3.z, fmaf(x1.w, c3.y, fmaf(x0.w, c3.x, a.w))));
    a.x = siluf(a.x); a.y = siluf(a.y); a.z = siluf(a.z); a.w = siluf(a.w);
    const ushort h0 = bf16r(a.x), h1 = bf16r(a.y), h2 = bf16r(a.z), h3 = bf16r(a.w);
    const ushort l0 = bf16r(a.x - bf2f(h0)), l1 = bf16r(a.y - bf2f(h1));
    const ushort l2 = bf16r(a.z - bf2f(h2)), l3 = bf16r(a.w - bf2f(h3));
    const int bi = r*NF + (n4 ^ ((r & 7) << 3));
    *(uint2*)&xch[bi] = make_uint2((uint)h0 | ((uint)h1 << 16), (uint)h2 | ((uint)h3 << 16));
    *(uint2*)&xcl[bi] = make_uint2((uint)l0 | ((uint)l1 << 16), (uint)l2 | ((uint)l3 << 16));
    if (r < lim) *(float4*)(xcc + ((size_t)sq*TL + t0 + r)*NF + n4) = a;
  }
  __syncthreads();   // sxr reads done; xch/xcl visible

  // xproj via MFMA: dbc[32 tok][32 outs], K=128, bf16x3. 12 mfma/wave.
  {
    const int w = tid >> 6, lane = tid & 63;
    const int cl = lane & 15, q8 = (lane >> 4) * 8;
    const int m = w & 1, nt = w >> 1;
    f32x4 acc = (f32x4){0.f,0.f,0.f,0.f};
    for (int c = 0; c < 4; ++c){
      const int r = m*16 + cl;
      const int ai = r*NF + ((c*32 + q8) ^ ((r & 7) << 3));
      const bf16x8 ah = *(const bf16x8*)&xch[ai];
      const bf16x8 al = *(const bf16x8*)&xcl[ai];
      const int o = nt*16 + cl;
      const size_t wo = (size_t)o*NF + c*32 + q8;
      const bf16x8 bh = *(const bf16x8*)(xwh + wo);
      const bf16x8 bl = *(const bf16x8*)(xwl + wo);
      acc = __builtin_amdgcn_mfma_f32_16x16x32_bf16(ah, bh, acc, 0, 0, 0);
      acc = __builtin_amdgcn_mfma_f32_16x16x32_bf16(al, bh, acc, 0, 0, 0);
      acc = __builtin_amdgcn_mfma_f32_16x16x32_bf16(ah, bl, acc, 0, 0, 0);
    }
    const int rb = m*16 + (lane >> 4)*4;
    const int o = nt*16 + cl;
    #pragma unroll
    for (int j = 0; j < 4; ++j)
      sdbc[(rb + j)*32 + o] = acc[j];
  }
  __syncthreads();

  // dt = softplus(dbc[:, :8] @ dw^T + db) -> sdt (aliases sxr) + dtb global
  #pragma unroll
  for (int i = 0; i < 16; ++i){
    const int e = tid + i*256;
    const int r = e >> 7, n = e & 127;
    const float4 b0 = *(const float4*)(sdbc + r*32);
    const float4 b1 = *(const float4*)(sdbc + r*32 + 4);
    const float4 w0 = *(const float4*)(dw + (size_t)n*8);
    const float4 w1 = *(const float4*)(dw + (size_t)n*8 + 4);
    float acc = db[n];
    acc = fmaf(b0.x, w0.x, acc); acc = fmaf(b0.y, w0.y, acc);
    acc = fmaf(b0.z, w0.z, acc); acc = fmaf(b0.w, w0.w, acc);
    acc = fmaf(b1.x, w1.x, acc); acc = fmaf(b1.y, w1.y, acc);
    acc = fmaf(b1.z, w1.z, acc); acc = fmaf(b1.w, w1.w, acc);
    const float dtv = softplusf(acc);
    sdt[e] = dtv;
    if (e < lim*NF) dtb[((size_t)sq*TL + t0)*NF + e] = dtv;
  }
  // B/C global writes
  for (int e = tid; e < CLEN*2*SD; e += 256){
    int r = e / (2*SD), c = e - r*2*SD;
    if (r < lim){
      float v = sdbc[r*32 + 8 + c];
      size_t tok = (size_t)sq*TL + t0 + r;
      if (c < SD) Bmb[tok*SD + c] = v;
      else        Cmb[tok*SD + (c - SD)] = v;
    }
  }
  __syncthreads();

  // scan pass 1 (power-trick dA with exact-exp fallback)
  {
    const int n = tid & 127, p = tid >> 7;
    float Av[6], h[6];
    #pragma unroll
    for (int s = 0; s < 6; ++s){
      Av[s] = -__expf(alog[(size_t)n*SD + p*6 + s]);
      h[s] = 0.f;
    }
    bool fast = true;
    #pragma unroll
    for (int s = 0; s < 6; ++s)
      fast = fast && (fabsf(Av[s] + (float)(p*6 + s + 1)) <= 1e-3f);
    float dts = 0.f;
    if (fast){
      for (int tt = 0; tt < lim; ++tt){
        const float dtv = sdt[tt*NF + n];
        const int xi = tt*NF + (n ^ ((tt & 7) << 3));
        const float xcv = bf2f((ushort)xch[xi]) + bf2f((ushort)xcl[xi]);
        float Bv[6];
        const float* br = sdbc + tt*32 + 8 + p*6;
        if (p == 0){
          const float4 a = *(const float4*)br;
          const float2 b = *(const float2*)(br + 4);
          Bv[0]=a.x; Bv[1]=a.y; Bv[2]=a.z; Bv[3]=a.w; Bv[4]=b.x; Bv[5]=b.y;
        } else {
          const float2 a = *(const float2*)br;
          const float4 b = *(const float4*)(br + 2);
          Bv[0]=a.x; Bv[1]=a.y; Bv[2]=b.x; Bv[3]=b.y; Bv[4]=b.z; Bv[5]=b.w;
        }
        const float dx = dtv * xcv;
        dts += dtv;
        const float q = __expf(-dtv);
        float dA;
        if (p == 0) dA = q;
        else { const float q2 = q*q; const float q4 = q2*q2; dA = q4*q2*q; }
        h[0] = fmaf(dA, h[0], dx*Bv[0]);
        #pragma unroll
        for (int s = 1; s < 6; ++s){ dA *= q; h[s] = fmaf(dA, h[s], dx*Bv[s]); }
      }
    } else {
      for (int tt = 0; tt < lim; ++tt){
        const float dtv = sdt[tt*NF + n];
        const int xi = tt*NF + (n ^ ((tt & 7) << 3));
        const float xcv = bf2f((ushort)xch[xi]) + bf2f((ushort)xcl[xi]);
        float Bv[6];
        const float* br = sdbc + tt*32 + 8 + p*6;
        if (p == 0){
          const float4 a = *(const float4*)br;
          const float2 b = *(const float2*)(br + 4);
          Bv[0]=a.x; Bv[1]=a.y; Bv[2]=a.z; Bv[3]=a.w; Bv[4]=b.x; Bv[5]=b.y;
        } else {
          const float2 a = *(const float2*)br;
          const float4 b = *(const float4*)(br + 2);
          Bv[0]=a.x; Bv[1]=a.y; Bv[2]=b.x; Bv[3]=b.y; Bv[4]=b.z; Bv[5]=b.w;
        }
        const float dx = dtv * xcv;
        dts += dtv;
        #pragma unroll
        for (int s = 0; s < 6; ++s){
          const float dA = __expf(dtv*Av[s]);
          h[s] = fmaf(dA, h[s], dx*Bv[s]);
        }
      }
    }
    const size_t base = (size_t)bid*SD*NF + n;
    #pragma unroll
    for (int s = 0; s < 6; ++s){
      ap [base + (p*6+s)*NF] = __expf(Av[s]*dts);
      hfb[base + (p*6+s)*NF] = h[s];
    }
  }
}

// ---- K3b: sequential combine across chunks
__global__ __launch_bounds__(128) void k_scan_combine(
    const float* __restrict__ ap, const float* __restrict__ hfb, float* __restrict__ hinit){
  const int sq = blockIdx.x;
  const int n = threadIdx.x;
  float h[SD];
  #pragma unroll
  for (int s = 0; s < SD; ++s) h[s] = 0.f;
  for (int c = 0; c < NCH; ++c){
    const size_t base = ((size_t)sq*NCH + c)*SD*NF + n;
    #pragma unroll
    for (int s = 0; s < SD; ++s){
      hinit[base + s*NF] = h[s];
      h[s] = fmaf(ap[base + s*NF], h[s], hfb[base + s*NF]);
    }
  }
}

// ---- K3c: scan pass 2 + gate (power-trick dA with fallback)
__global__ __launch_bounds__(128) void k_scan_pass2(
    const float* __restrict__ dtb, const float* __restrict__ xcc,
    const float* __restrict__ Bmb, const float* __restrict__ Cmb,
    const float* __restrict__ alog, const float* __restrict__ hinit,
    const float* __restrict__ zb, const float* __restrict__ Dv,
    float* __restrict__ yb){
  const int bid = blockIdx.x;
  const int sq = bid / NCH, c = bid - sq*NCH;
  const int t0 = c*CLEN;
  const int lim = (TL - t0 < CLEN) ? (TL - t0) : CLEN;
  const int n = threadIdx.x;
  const float4* A4 = (const float4*)(alog + (size_t)n*SD);
  float4 Aa = A4[0], Ab = A4[1], Ac = A4[2];
  float Av[SD] = {Aa.x,Aa.y,Aa.z,Aa.w, Ab.x,Ab.y,Ab.z,Ab.w, Ac.x,Ac.y,Ac.z,Ac.w};
  #pragma unroll
  for (int s = 0; s < SD; ++s) Av[s] = -__expf(Av[s]);
  bool fast = true;
  #pragma unroll
  for (int s = 0; s < SD; ++s)
    fast = fast && (fabsf(Av[s] + (float)(s + 1)) <= 1e-3f);
  const float dvn = Dv[n];
  float h[SD];
  const size_t hbase = (size_t)bid*SD*NF + n;
  #pragma unroll
  for (int s = 0; s < SD; ++s) h[s] = hinit[hbase + s*NF];
  const size_t tok0 = (size_t)sq*TL + t0;
  if (fast){
    for (int tt = 0; tt < lim; ++tt){
      const size_t tok = tok0 + tt;
      float dtv = dtb[tok*NF + n];
      float xcv = xcc[tok*NF + n];
      float dx  = dtv * xcv;
      const float4* B4 = (const float4*)(Bmb + tok*SD);
      const float4* C4 = (const float4*)(Cmb + tok*SD);
      float4 Ba=B4[0], Bb=B4[1], Bc=B4[2];
      float4 Ca=C4[0], Cb=C4[1], Cc=C4[2];
      float Bv[SD] = {Ba.x,Ba.y,Ba.z,Ba.w, Bb.x,Bb.y,Bb.z,Bb.w, Bc.x,Bc.y,Bc.z,Bc.w};
      float Cv[SD] = {Ca.x,Ca.y,Ca.z,Ca.w, Cb.x,Cb.y,Cb.z,Cb.w, Cc.x,Cc.y,Cc.z,Cc.w};
      const float q = __expf(-dtv);
      float dA = q;
      float yv = 0.f;
      h[0] = fmaf(dA, h[0], dx*Bv[0]);
      yv = fmaf(h[0], Cv[0], yv);
      #pragma unroll
      for (int s = 1; s < SD; ++s){
        dA *= q;
        h[s] = fmaf(dA, h[s], dx*Bv[s]);
        yv = fmaf(h[s], Cv[s], yv);
      }
      float zv = zb[tok*NF + n];
      yb[tok*NF + n] = fmaf(dvn, xcv, yv) * siluf(zv);
    }
  } else {
    for (int tt = 0; tt < lim; ++tt){
      const size_t tok = tok0 + tt;
      float dtv = dtb[tok*NF + n];
      float xcv = xcc[tok*NF + n];
      float dx  = dtv * xcv;
      const float4* B4 = (const float4*)(Bmb + tok*SD);
      const float4* C4 = (const float4*)(Cmb + tok*SD);
      float4 Ba=B4[0], Bb=B4[1], Bc=B4[2];
      float4 Ca=C4[0], Cb=C4[1], Cc=C4[2];
      float Bv[SD] = {Ba.x,Ba.y,Ba.z,Ba.w, Bb.x,Bb.y,Bb.z,Bb.w, Bc.x,Bc.y,Bc.z,Bc.w};
      float Cv[SD] = {Ca.x,Ca.y,Ca.z,Ca.w, Cb.x,Cb.y,Cb.z,Cb.w, Cc.x,Cc.y,Cc.z,Cc.w};
      float yv = 0.f;
      #pragma unroll
      for (int s = 0; s < SD; ++s){
        float dA = __expf(dtv*Av[s]);
        h[s] = fmaf(dA, h[s], dx*Bv[s]);
        yv = fmaf(h[s], Cv[s], yv);
      }
      float zv = zb[tok*NF + n];
      yb[tok*NF + n] = fmaf(dvn, xcv, yv) * siluf(zv);
    }
  }
}

// ---- K4 (R7 known-good): seq += yb @ ow^T + ob via MFMA bf16x3.
__global__ __launch_bounds__(256) void k_gate_out(
    const float* __restrict__ yb,
    const ushort* __restrict__ wh, const ushort* __restrict__ wl, const float* __restrict__ ob,
    float* __restrict__ seq){
  __shared__ short xsh[MT*NF];
  __shared__ short xsl[MT*NF];
  const int tid = threadIdx.x;
  const int tok0 = blockIdx.x * MT;

  #pragma unroll
  for (int i = 0; i < 8; ++i){
    const int r  = (tid & 15) + ((i & 3) << 4);
    const int nq = (tid >> 4) + ((i >> 2) << 4);
    const int tok = tok0 + r;
    float4 v = make_float4(0.f,0.f,0.f,0.f);
    if (tok < NTOK) v = *(const float4*)(yb + (size_t)tok*NF + nq*4);
    const ushort h0 = bf16r(v.x), h1 = bf16r(v.y), h2 = bf16r(v.z), h3 = bf16r(v.w);
    const ushort l0 = bf16r(v.x - bf2f(h0)), l1 = bf16r(v.y - bf2f(h1));
    const ushort l2 = bf16r(v.z - bf2f(h2)), l3 = bf16r(v.w - bf2f(h3));
    const int hi = r*NF + ((nq*4) ^ ((r & 7) << 3));
    *(uint2*)&xsh[hi] = make_uint2((uint)h0 | ((uint)h1 << 16), (uint)h2 | ((uint)h3 << 16));
    *(uint2*)&xsl[hi] = make_uint2((uint)l0 | ((uint)l1 << 16), (uint)l2 | ((uint)l3 << 16));
  }
  __syncthreads();

  const int w = tid >> 6, lane = tid & 63;
  const int cl = lane & 15, q8 = (lane >> 4) * 8;
  const int obase = w * 32;
  f32x4 acc[4][2];
  #pragma unroll
  for (int m = 0; m < 4; ++m)
    #pragma unroll
    for (int nt = 0; nt < 2; ++nt) acc[m][nt] = (f32x4){0.f,0.f,0.f,0.f};

  for (int c = 0; c < 4; ++c){
    bf16x8 ah[4], al[4];
    #pragma unroll
    for (int m = 0; m < 4; ++m){
      const int r = m*16 + cl;
      const int hi = r*NF + ((c*32 + q8) ^ ((r & 7) << 3));
      ah[m] = *(const bf16x8*)&xsh[hi];
      al[m] = *(const bf16x8*)&xsl[hi];
    }
    #pragma unroll
    for (int nt = 0; nt < 2; ++nt){
      const int o = obase + nt*16 + cl;
      const size_t wo = (size_t)o*NF + c*32 + q8;
      const bf16x8 bh = *(const bf16x8*)(wh + wo);
      const bf16x8 bl = *(const bf16x8*)(wl + wo);
      #pragma unroll
      for (int m = 0; m < 4; ++m){
        acc[m][nt] = __builtin_amdgcn_mfma_f32_16x16x32_bf16(ah[m], bh, acc[m][nt], 0, 0, 0);
        acc[m][nt] = __builtin_amdgcn_mfma_f32_16x16x32_bf16(al[m], bh, acc[m][nt], 0, 0, 0);
        acc[m][nt] = __builtin_amdgcn_mfma_f32_16x16x32_bf16(ah[m], bl, acc[m][nt], 0, 0, 0);
      }
    }
  }

  const int rbase = (lane >> 4) * 4;
  #pragma unroll
  for (int nt = 0; nt < 2; ++nt){
    const int o = obase + nt*16 + cl;
    const float bias = ob[o];
    #pragma unroll
    for (int m = 0; m < 4; ++m)
      #pragma unroll
      for (int j2 = 0; j2 < 4; ++j2){
        const int tok = tok0 + m*16 + rbase + j2;
        if (tok < NTOK){
          float* dst = seq + (size_t)tok*NF + o;
          *dst = *dst + acc[m][nt][j2] + bias;
        }
      }
  }
}

// ---- K5a (R7 known-good): cross = main @ cb_w^T + cb_b via MFMA bf16x3.
__global__ __launch_bounds__(256) void k_cross_gemm(
    const float* __restrict__ seq,
    const ushort* __restrict__ wh, const ushort* __restrict__ wl, const float* __restrict__ cbb,
    float* __restrict__ cross){
  __shared__ short xsh[MT*NF];
  __shared__ short xsl[MT*NF];
  const int tid = threadIdx.x;
  const int tok0 = blockIdx.x * MT;

  #pragma unroll
  for (int i = 0; i < 8; ++i){
    const int r  = (tid & 15) + ((i & 3) << 4);
    const int nq = (tid >> 4) + ((i >> 2) << 4);
    const int tok = tok0 + r;
    float4 v = make_float4(0.f,0.f,0.f,0.f);
    if (tok < NTOK){
      int b = tok / 30000, rr = tok - b*30000;
      int t = rr / 30, k = rr - t*30;
      v = *(const float4*)(seq + ((size_t)(b*30 + k)*TL + t)*NF + nq*4);
    }
    const ushort h0 = bf16r(v.x), h1 = bf16r(v.y), h2 = bf16r(v.z), h3 = bf16r(v.w);
    const ushort l0 = bf16r(v.x - bf2f(h0)), l1 = bf16r(v.y - bf2f(h1));
    const ushort l2 = bf16r(v.z - bf2f(h2)), l3 = bf16r(v.w - bf2f(h3));
    const int hi = r*NF + ((nq*4) ^ ((r & 7) << 3));
    *(uint2*)&xsh[hi] = make_uint2((uint)h0 | ((uint)h1 << 16), (uint)h2 | ((uint)h3 << 16));
    *(uint2*)&xsl[hi] = make_uint2((uint)l0 | ((uint)l1 << 16), (uint)l2 | ((uint)l3 << 16));
  }
  __syncthreads();

  const int w = tid >> 6, lane = tid & 63;
  const int cl = lane & 15, q8 = (lane >> 4) * 8;
  const int obase = w * 32;
  f32x4 acc[4][2];
  #pragma unroll
  for (int m = 0; m < 4; ++m)
    #pragma unroll
    for (int nt = 0; nt < 2; ++nt) acc[m][nt] = (f32x4){0.f,0.f,0.f,0.f};

  for (int c = 0; c < 4; ++c){
    bf16x8 ah[4], al[4];
    #pragma unroll
    for (int m = 0; m < 4; ++m){
      const int r = m*16 + cl;
      const int hi = r*NF + ((c*32 + q8) ^ ((r & 7) << 3));
      ah[m] = *(const bf16x8*)&xsh[hi];
      al[m] = *(const bf16x8*)&xsl[hi];
    }
    #pragma unroll
    for (int nt = 0; nt < 2; ++nt){
      const int o = obase + nt*16 + cl;
      const size_t wo = (size_t)o*NF + c*32 + q8;
      const bf16x8 bh = *(const bf16x8*)(wh + wo);
      const bf16x8 bl = *(const bf16x8*)(wl + wo);
      #pragma unroll
      for (int m = 0; m < 4; ++m){
        acc[m][nt] = __builtin_amdgcn_mfma_f32_16x16x32_bf16(ah[m], bh, acc[m][nt], 0, 0, 0);
        acc[m][nt] = __builtin_amdgcn_mfma_f32_16x16x32_bf16(al[m], bh, acc[m][nt], 0, 0, 0);
        acc[m][nt] = __builtin_amdgcn_mfma_f32_16x16x32_bf16(ah[m], bl, acc[m][nt], 0, 0, 0);
      }
    }
  }

  const int rbase = (lane >> 4) * 4;
  #pragma unroll
  for (int nt = 0; nt < 2; ++nt){
    const int o = obase + nt*16 + cl;
    const float bias = cbb[o];
    #pragma unroll
    for (int m = 0; m < 4; ++m)
      #pragma unroll
      for (int j2 = 0; j2 < 4; ++j2){
        const int tok = tok0 + m*16 + rbase + j2;
        if (tok < NTOK) cross[(size_t)tok*NF + o] = acc[m][nt][j2] + bias;
      }
  }
}

// ---- K5b: LN1 -> gelu -> +main -> LN2 -> transposed write. 32 tokens/block.
__global__ __launch_bounds__(256) void k_cross_ln(
    const float* __restrict__ seq, const float* __restrict__ cross,
    const float* __restrict__ clnw, const float* __restrict__ clnb,
    const float* __restrict__ flnw, const float* __restrict__ flnb,
    float* __restrict__ out){
  __shared__ float fs[32*LNP];
  const int tid = threadIdx.x;
  const int tok0 = blockIdx.x * 32;
  const int j16 = tid >> 4, l16 = tid & 15;

  for (int it = 0; it < 2; ++it){
    const int jj = j16 + 16*it;
    const int tok = tok0 + jj;
    const int b = tok / 30000, rr = tok - b*30000;
    const int t = rr / 30, k = rr - t*30;
    const float* cp = cross + (size_t)tok*NF;
    const float* mp = seq + ((size_t)(b*30 + k)*TL + t)*NF;
    float cv[8]; float s = 0.f, s2 = 0.f;
    #pragma unroll
    for (int i = 0; i < 8; ++i){
      float f = cp[l16 + 16*i]; cv[i] = f; s += f; s2 += f*f;
    }
    #pragma unroll
    for (int m = 1; m < 16; m <<= 1){ s += __shfl_xor(s, m, 64); s2 += __shfl_xor(s2, m, 64); }
    float mu = s * (1.f/128.f);
    float rs = rsqrtf(s2*(1.f/128.f) - mu*mu + 1e-5f);
    float rv[8]; float rsum = 0.f, rsum2 = 0.f;
    #pragma unroll
    for (int i = 0; i < 8; ++i){
      int n = l16 + 16*i;
      float cn = (cv[i] - mu)*rs*clnw[n] + clnb[n];
      float g = 0.5f*cn*(1.f + erff(cn*0.70710678118f));
      float res = mp[n] + g;
      rv[i] = res; rsum += res; rsum2 += res*res;
    }
    #pragma unroll
    for (int m = 1; m < 16; m <<= 1){ rsum += __shfl_xor(rsum, m, 64); rsum2 += __shfl_xor(rsum2, m, 64); }
    float mu2 = rsum * (1.f/128.f);
    float rs2 = rsqrtf(rsum2*(1.f/128.f) - mu2*mu2 + 1e-5f);
    #pragma unroll
    for (int i = 0; i < 8; ++i){
      int n = l16 + 16*i;
      fs[jj*LNP + n] = (rv[i] - mu2)*rs2*flnw[n] + flnb[n];
    }
  }
  __syncthreads();

  #pragma unroll
  for (int i = 0; i < 16; ++i){
    const int e = tid + i*256;
    const int j = e & 31, n = e >> 5;
    const int tok = tok0 + j;
    const int b = tok / 30000, rr = tok - b*30000;
    out[(size_t)(b*NF + n)*30000 + rr] = fs[j*LNP + n];
  }
}

extern "C" void kernel_launch(void* const* d_in, const int* in_sizes, int n_in,
                              void* d_out, int out_size, void* d_ws, size_t ws_size,
                              hipStream_t stream){
  const float* x       = (const float*)d_in[0];
  const float* ln_w    = (const float*)d_in[1];
  const float* ln_b    = (const float*)d_in[2];
  const float* in_w    = (const float*)d_in[3];
  const float* in_b    = (const float*)d_in[4];
  const float* conv_w  = (const float*)d_in[5];
  const float* conv_b  = (const float*)d_in[6];
  const float* xp_w    = (const float*)d_in[7];
  const float* dtp_w   = (const float*)d_in[8];
  const float* dtp_b   = (const float*)d_in[9];
  const float* A_log   = (const float*)d_in[10];
  const float* Dv      = (const float*)d_in[11];
  const float* out_w   = (const float*)d_in[12];
  const float* out_b   = (const float*)d_in[13];
  const float* cb_w    = (const float*)d_in[14];
  const float* cb_b    = (const float*)d_in[15];
  const float* cb_ln_w = (const float*)d_in[16];
  const float* cb_ln_b = (const float*)d_in[17];
  const float* fin_ln_w= (const float*)d_in[18];
  const float* fin_ln_b= (const float*)d_in[19];
  float* out = (float*)d_out;

  const size_t SEQSZ = (size_t)BKS*TL*NF;        // 7,680,000 floats
  const size_t CHSZ  = (size_t)BKS*NF*NCH*SD;    // 2,949,120 floats
  const size_t FBASE = 6*SEQSZ + 2*(size_t)BKS*TL*SD;   // fp32 region
  const size_t BASE  = FBASE + WCNT;                    // + bf16 pool (2*WCNT ushorts)
  float* ws  = (float*)d_ws;
  float* seq = ws;
  float* xcr = ws + SEQSZ;
  float* zb  = ws + 2*SEQSZ;
  float* xcc = ws + 3*SEQSZ;
  float* dtb = ws + 4*SEQSZ;
  float* yb  = ws + 5*SEQSZ;
  float* Bmb = ws + 6*SEQSZ;
  float* Cmb = Bmb + (size_t)BKS*TL*SD;
  ushort* wbh = (ushort*)(ws + FBASE);
  ushort* wbl = wbh + WCNT;
  if (ws_size < BASE*sizeof(float)) return;

  // Liveness aliasing: ap/hfb -> yb region; hinit -> xcr; cross -> dtb.
  float* ap    = yb;
  float* hfb   = yb + CHSZ;
  float* hinit = xcr;
  float* cross = dtb;

  k_wconv<<<(WCNT + 255)/256, 256, 0, stream>>>(in_w, out_w, cb_w, xp_w, wbh, wbl);
  k_ingest<<<2*TL, 256, 0, stream>>>(x, seq);
  for (int l = 0; l < 4; ++l){
    k_ln_inproj<<<NBLK, 256, 0, stream>>>(seq, ln_w + l*NF, ln_b + l*NF,
        wbh + (size_t)l*32768, wbl + (size_t)l*32768, in_b + l*2*NF, xcr, zb);
    k_conv_scan1<<<BKS*NCH, 256, 0, stream>>>(xcr, conv_w + (size_t)l*NF*4, conv_b + l*NF,
        wbh + OFF_XW + (size_t)l*4096, wbl + OFF_XW + (size_t)l*4096,
        dtp_w + (size_t)l*NF*RD, dtp_b + l*NF,
        A_log + (size_t)l*NF*SD, xcc, dtb, Bmb, Cmb, ap, hfb);
    k_scan_combine<<<BKS, NF, 0, stream>>>(ap, hfb, hinit);
    k_scan_pass2<<<BKS*NCH, NF, 0, stream>>>(dtb, xcc, Bmb, Cmb, A_log + (size_t)l*NF*SD,
        hinit, zb, Dv + l*NF, yb);
    k_gate_out<<<NBLK, 256, 0, stream>>>(yb,
        wbh + OFF_OW + (size_t)l*16384, wbl + OFF_OW + (size_t)l*16384, out_b + l*NF, seq);
  }
  k_cross_gemm<<<NBLK, 256, 0, stream>>>(seq, wbh + OFF_CBW, wbl + OFF_CBW, cb_b, cross);
  k_cross_ln<<<NTOK/32, 256, 0, stream>>>(seq, cross, cb_ln_w, cb_ln_b, fin_ln_w, fin_ln_b, out);
}